// Round 2
// 856.218 us; speedup vs baseline: 1.0317x; 1.0317x over previous
//
#include <hip/hip_runtime.h>

#define NN 100000
#define NE 1600000
#define BN_EPS 1e-5f

// CSR binning parameters
#define BSH 7
#define BSZ (1 << BSH)   // 128 dsts per bucket
#define NBUCK 782        // divup(NN, BSZ)
#define NC 192           // edge chunks
#define CE 8334          // divup(NE, NC)

typedef _Float16 half1;
typedef _Float16 half4 __attribute__((ext_vector_type(4)));
typedef _Float16 h8 __attribute__((ext_vector_type(8)));
typedef float f4 __attribute__((ext_vector_type(4)));
typedef float f8 __attribute__((ext_vector_type(8)));

static inline int divup(int a, int b) { return (a + b - 1) / b; }

// per-edge source weight from packed entry: src in [0:17), deg_src in [17:32)
__device__ __forceinline__ float wsrc(unsigned int q) {
    unsigned int dg = q >> 17;
    return dg ? rsqrtf((float)dg) : 0.f;
}

// ---------------- preprocessing ----------------

// fused: global degree histogram + per-chunk bucket histogram
__global__ void hist2_kernel(const int* __restrict__ dst, int* __restrict__ deg,
                             int* __restrict__ hist_g) {
    __shared__ int h[NBUCK];
    int c = blockIdx.x;
    for (int i = threadIdx.x; i < NBUCK; i += blockDim.x) h[i] = 0;
    __syncthreads();
    int e0 = c * CE, e1 = min(e0 + CE, NE);
    for (int e = e0 + threadIdx.x; e < e1; e += blockDim.x) {
        int d = dst[e];
        atomicAdd(&deg[d], 1);
        atomicAdd(&h[d >> BSH], 1);
    }
    __syncthreads();
    for (int i = threadIdx.x; i < NBUCK; i += blockDim.x) hist_g[c * NBUCK + i] = h[i];
}

__global__ void blksum_kernel(const int* __restrict__ deg, int* __restrict__ blk, int n) {
    __shared__ int red[256];
    int t = threadIdx.x;
    int base = blockIdx.x * 1024 + t * 4;
    int s = 0;
#pragma unroll
    for (int i = 0; i < 4; ++i) {
        int idx = base + i;
        if (idx < n) s += deg[idx];
    }
    red[t] = s;
    __syncthreads();
    for (int off = 128; off > 0; off >>= 1) {
        if (t < off) red[t] += red[t + off];
        __syncthreads();
    }
    if (t == 0) blk[blockIdx.x] = red[0];
}

__global__ void blkscan_kernel(int* __restrict__ blk, int nb, int* __restrict__ row_ptr, int n) {
    __shared__ int sh[256];
    int t = threadIdx.x;
    int v = (t < nb) ? blk[t] : 0;
    sh[t] = v;
    __syncthreads();
    for (int off = 1; off < 256; off <<= 1) {
        int u = (t >= off) ? sh[t - off] : 0;
        __syncthreads();
        sh[t] += u;
        __syncthreads();
    }
    if (t < nb) blk[t] = (t == 0) ? 0 : sh[t - 1];
    if (t == nb - 1) row_ptr[n] = sh[t];
}

__global__ void emit_kernel(const int* __restrict__ deg, const int* __restrict__ blk,
                            int* __restrict__ row_ptr, int n) {
    __shared__ int red[256];
    int t = threadIdx.x;
    int base = blockIdx.x * 1024 + t * 4;
    int d[4];
    int s = 0;
#pragma unroll
    for (int i = 0; i < 4; ++i) {
        int idx = base + i;
        d[i] = (idx < n) ? deg[idx] : 0;
        s += d[i];
    }
    red[t] = s;
    __syncthreads();
    for (int off = 1; off < 256; off <<= 1) {
        int u = (t >= off) ? red[t - off] : 0;
        __syncthreads();
        red[t] += u;
        __syncthreads();
    }
    int run = blk[blockIdx.x] + ((t == 0) ? 0 : red[t - 1]);
#pragma unroll
    for (int i = 0; i < 4; ++i) {
        int idx = base + i;
        if (idx < n) { row_ptr[idx] = run; run += d[i]; }
    }
}

// off_g[c][b] = row_ptr[b*BSZ] + sum_{c'<c} hist_g[c'][b]
__global__ void bucketoff_kernel(const int* __restrict__ row_ptr, const int* __restrict__ hist_g,
                                 int* __restrict__ off_g) {
    int b = blockIdx.x * blockDim.x + threadIdx.x;
    if (b >= NBUCK) return;
    int run = row_ptr[b << BSH];  // b*128 < NN for all buckets
#pragma unroll 4
    for (int c = 0; c < NC; ++c) {
        off_g[c * NBUCK + b] = run;
        run += hist_g[c * NBUCK + b];
    }
}

// XCD-pinned bucket scatter: block (chunk c, xcd x) handles buckets with (b&7)==x.
// All its writes land in ~1.6MB of bucket regions owned by this XCD -> L2 write-combined.
// Positions from LDS atomics (no global atomics). Correct regardless of actual
// blockIdx->XCD mapping (pinning is a locality hint only).
__global__ void binscatter_kernel(const int* __restrict__ src, const int* __restrict__ dst,
                                  const int* __restrict__ deg, const int* __restrict__ off_g,
                                  int2* __restrict__ tmp) {
    __shared__ int off_l[NBUCK];
    int myx = blockIdx.x & 7;
    int c = blockIdx.x >> 3;
    for (int i = threadIdx.x; i < NBUCK; i += blockDim.x)
        off_l[i] = ((i & 7) == myx) ? off_g[c * NBUCK + i] : 0;
    __syncthreads();
    int e0 = c * CE, e1 = min(e0 + CE, NE);
    for (int e = e0 + threadIdx.x; e < e1; e += blockDim.x) {
        int d = dst[e];
        int b = d >> BSH;
        if ((b & 7) != myx) continue;
        int s = src[e];
        int dg = deg[s];
        if (dg > 32767) dg = 32767;
        int pos = atomicAdd(&off_l[b], 1);
        tmp[pos] = make_int2(s | (dg << 17), d & (BSZ - 1));
    }
}

// per-bucket fine permutation into exact CSR order; 4B packed entries
__global__ void finalize_kernel(const int2* __restrict__ tmp, const int* __restrict__ row_ptr,
                                unsigned int* __restrict__ cw) {
    __shared__ int cnt[BSZ];
    int b = blockIdx.x;
    for (int i = threadIdx.x; i < BSZ; i += blockDim.x) cnt[i] = 0;
    __syncthreads();
    int base = b << BSH;
    int e0 = row_ptr[base];
    int e1 = row_ptr[min(base + BSZ, NN)];
    for (int e = e0 + threadIdx.x; e < e1; e += blockDim.x) {
        int2 r = tmp[e];
        int d = base + r.y;
        int k = atomicAdd(&cnt[r.y], 1);
        cw[row_ptr[d] + k] = (unsigned int)r.x;
    }
}

// ---------------- fp16 converts for MFMA ----------------

__global__ void cvtx_kernel(const float4* __restrict__ X, half4* __restrict__ Xh, int tot4) {
    int i = blockIdx.x * blockDim.x + threadIdx.x;
    if (i >= tot4) return;
    float4 v = X[i];
    half4 h;
    h.x = (half1)v.x; h.y = (half1)v.y; h.z = (half1)v.z; h.w = (half1)v.w;
    Xh[i] = h;
}

// Wt[og][kd] = W1[og>>6][kd][og&63], fp16 ; Wt is [512][128]
__global__ void transw_kernel(const float* __restrict__ W, half1* __restrict__ Wt) {
    int i = blockIdx.x * blockDim.x + threadIdx.x;
    if (i >= 512 * 128) return;
    int kd = i >> 9;
    int og = i & 511;
    int k = og >> 6, o = og & 63;
    Wt[(size_t)og * 128 + kd] = (half1)W[((size_t)k * 128 + kd) * 64 + o];
}

// ---------------- W padding ----------------
__global__ void padw_kernel(const float* __restrict__ src, float* __restrict__ dst,
                            int K, int dins, int douts, int dind, int doutd) {
    int i = blockIdx.x * blockDim.x + threadIdx.x;
    int tot = K * dind * doutd;
    if (i >= tot) return;
    int o = i % doutd;
    int r = i / doutd;
    int dd = r % dind;
    int k = r / dind;
    dst[i] = (dd < dins && o < douts) ? src[((size_t)k * dins + dd) * douts + o] : 0.f;
}

// ---------------- Clenshaw prop, h8 (16B) gathers — dim == 64 ----------------
__global__ void proph8_kernel(const h8* __restrict__ feat, const h8* __restrict__ sub,
                              const h8* __restrict__ add, h8* __restrict__ outh,
                              f8* __restrict__ outf,
                              const int* __restrict__ row_ptr, const unsigned int* __restrict__ cw,
                              int n, float scale, int has_sub, int bnrelu,
                              const float* __restrict__ bn_g, const float* __restrict__ bn_b,
                              const float* __restrict__ bn_m, const float* __restrict__ bn_v) {
    int idx = blockIdx.x * blockDim.x + threadIdx.x;
    if (idx >= n * 8) return;
    int nd = idx >> 3;
    int f = idx & 7;
    int e0 = row_ptr[nd], e1 = row_ptr[nd + 1];
    f8 a0 = {0.f, 0.f, 0.f, 0.f, 0.f, 0.f, 0.f, 0.f}, a1 = a0, a2 = a0, a3 = a0;
    int e = e0;
    for (; e + 4 <= e1; e += 4) {
        unsigned int q0 = cw[e], q1 = cw[e + 1], q2 = cw[e + 2], q3 = cw[e + 3];
        f8 v0 = __builtin_convertvector(feat[(size_t)(q0 & 0x1FFFFu) * 8 + f], f8);
        f8 v1 = __builtin_convertvector(feat[(size_t)(q1 & 0x1FFFFu) * 8 + f], f8);
        f8 v2 = __builtin_convertvector(feat[(size_t)(q2 & 0x1FFFFu) * 8 + f], f8);
        f8 v3 = __builtin_convertvector(feat[(size_t)(q3 & 0x1FFFFu) * 8 + f], f8);
        a0 += wsrc(q0) * v0;
        a1 += wsrc(q1) * v1;
        a2 += wsrc(q2) * v2;
        a3 += wsrc(q3) * v3;
    }
    for (; e < e1; ++e) {
        unsigned int q = cw[e];
        a0 += wsrc(q) * __builtin_convertvector(feat[(size_t)(q & 0x1FFFFu) * 8 + f], f8);
    }
    int degd = e1 - e0;
    float ms = (degd > 0) ? -scale * rsqrtf((float)degd) : 0.f;
    f8 r = ((a0 + a1) + (a2 + a3)) * ms;
    if (has_sub) r -= __builtin_convertvector(sub[idx], f8);
    r += __builtin_convertvector(add[idx], f8);
    if (bnrelu) {
#pragma unroll
        for (int c = 0; c < 8; ++c) {
            int o = f * 8 + c;
            float sc = bn_g[o] * rsqrtf(bn_v[o] + BN_EPS);
            r[c] = fmaxf(fmaf(r[c] - bn_m[o], sc, bn_b[o]), 0.f);
        }
    }
    if (outf) {
        outf[idx] = r;
    } else {
        outh[idx] = __builtin_convertvector(r, h8);
    }
}

// ---------------- Clenshaw prop, half4 gathers — small dims ----------------
__global__ void proph_kernel(const half4* __restrict__ feat, const half4* __restrict__ sub,
                             const half4* __restrict__ add, half4* __restrict__ outh,
                             f4* __restrict__ outf,
                             const int* __restrict__ row_ptr, const unsigned int* __restrict__ cw,
                             int n, int dim4, float scale, int has_sub,
                             int bnrelu, int used,
                             const float* __restrict__ bn_g, const float* __restrict__ bn_b,
                             const float* __restrict__ bn_m, const float* __restrict__ bn_v) {
    int idx = blockIdx.x * blockDim.x + threadIdx.x;
    if (idx >= n * dim4) return;
    int nd = idx / dim4;
    int f = idx - nd * dim4;
    int e0 = row_ptr[nd], e1 = row_ptr[nd + 1];
    f4 a0 = {0.f, 0.f, 0.f, 0.f}, a1 = a0, a2 = a0, a3 = a0;
    int e = e0;
    for (; e + 4 <= e1; e += 4) {
        unsigned int q0 = cw[e], q1 = cw[e + 1], q2 = cw[e + 2], q3 = cw[e + 3];
        f4 v0 = __builtin_convertvector(feat[(size_t)(q0 & 0x1FFFFu) * dim4 + f], f4);
        f4 v1 = __builtin_convertvector(feat[(size_t)(q1 & 0x1FFFFu) * dim4 + f], f4);
        f4 v2 = __builtin_convertvector(feat[(size_t)(q2 & 0x1FFFFu) * dim4 + f], f4);
        f4 v3 = __builtin_convertvector(feat[(size_t)(q3 & 0x1FFFFu) * dim4 + f], f4);
        a0 += wsrc(q0) * v0;
        a1 += wsrc(q1) * v1;
        a2 += wsrc(q2) * v2;
        a3 += wsrc(q3) * v3;
    }
    for (; e < e1; ++e) {
        unsigned int q = cw[e];
        a0 += wsrc(q) * __builtin_convertvector(feat[(size_t)(q & 0x1FFFFu) * dim4 + f], f4);
    }
    int degd = e1 - e0;
    float ms = (degd > 0) ? -scale * rsqrtf((float)degd) : 0.f;
    f4 r = ((a0 + a1) + (a2 + a3)) * ms;
    if (has_sub) r -= __builtin_convertvector(sub[idx], f4);
    r += __builtin_convertvector(add[idx], f4);
    if (bnrelu) {
#pragma unroll
        for (int c = 0; c < 4; ++c) {
            int o = f * 4 + c;
            if (o < used) {
                float sc = bn_g[o] * rsqrtf(bn_v[o] + BN_EPS);
                r[c] = fmaxf(fmaf(r[c] - bn_m[o], sc, bn_b[o]), 0.f);
            } else r[c] = 0.f;
        }
    }
    if (outf) {
        outf[idx] = r;
    } else {
        half4 h;
        h.x = (half1)r.x; h.y = (half1)r.y; h.z = (half1)r.z; h.w = (half1)r.w;
        outh[idx] = h;
    }
}

// layer-4 final: fp16 gathers/streams at stride 12 (dim4=3), fp32 out at stride 10
__global__ void propl_kernel(const half4* __restrict__ feat, const half4* __restrict__ sub,
                             const half4* __restrict__ add, float* __restrict__ out,
                             const int* __restrict__ row_ptr, const unsigned int* __restrict__ cw,
                             int n) {
    int idx = blockIdx.x * blockDim.x + threadIdx.x;
    if (idx >= n * 3) return;
    int nd = idx / 3;
    int f = idx - nd * 3;
    int e0 = row_ptr[nd], e1 = row_ptr[nd + 1];
    f4 a0 = {0.f, 0.f, 0.f, 0.f}, a1 = a0, a2 = a0, a3 = a0;
    int e = e0;
    for (; e + 4 <= e1; e += 4) {
        unsigned int q0 = cw[e], q1 = cw[e + 1], q2 = cw[e + 2], q3 = cw[e + 3];
        a0 += wsrc(q0) * __builtin_convertvector(feat[(size_t)(q0 & 0x1FFFFu) * 3 + f], f4);
        a1 += wsrc(q1) * __builtin_convertvector(feat[(size_t)(q1 & 0x1FFFFu) * 3 + f], f4);
        a2 += wsrc(q2) * __builtin_convertvector(feat[(size_t)(q2 & 0x1FFFFu) * 3 + f], f4);
        a3 += wsrc(q3) * __builtin_convertvector(feat[(size_t)(q3 & 0x1FFFFu) * 3 + f], f4);
    }
    for (; e < e1; ++e) {
        unsigned int q = cw[e];
        a0 += wsrc(q) * __builtin_convertvector(feat[(size_t)(q & 0x1FFFFu) * 3 + f], f4);
    }
    int degd = e1 - e0;
    float ms = (degd > 0) ? -rsqrtf((float)degd) : 0.f;
    f4 r = ((a0 + a1) + (a2 + a3)) * ms;
    r -= __builtin_convertvector(sub[idx], f4);
    r += __builtin_convertvector(add[idx], f4);
    int o = f * 4;
    float* orow = out + (size_t)nd * 10;
    if (o + 0 < 10) orow[o + 0] = r.x;
    if (o + 1 < 10) orow[o + 1] = r.y;
    if (o + 2 < 10) orow[o + 2] = r.z;
    if (o + 3 < 10) orow[o + 3] = r.w;
}

// ---------------- layer-1 GEMM via MFMA (swapped operands) ----------------
__global__ __launch_bounds__(256) void gemm_mfma_kernel(
        const half1* __restrict__ Xh, const half1* __restrict__ Wt,
        const float* __restrict__ bias, half1* __restrict__ CB, int n) {
    int lane = threadIdx.x & 63;
    int wave = threadIdx.x >> 6;
    int m16 = lane & 15;
    int quad = lane >> 4;
    int ks = blockIdx.y * 4 + wave;
    int ntile = blockIdx.x * 64;

    f4 acc[4][4];
#pragma unroll
    for (int nt = 0; nt < 4; ++nt)
#pragma unroll
        for (int i = 0; i < 4; ++i) acc[nt][i] = (f4){0.f, 0.f, 0.f, 0.f};

#pragma unroll
    for (int kc = 0; kc < 4; ++kc) {
        int koff = kc * 32 + quad * 8;
        h8 a[4];
#pragma unroll
        for (int i = 0; i < 4; ++i)
            a[i] = *(const h8*)(Wt + (size_t)(ks * 64 + i * 16 + m16) * 128 + koff);
        h8 b[4];
#pragma unroll
        for (int nt = 0; nt < 4; ++nt) {
            int node = min(ntile + nt * 16 + m16, n - 1);
            b[nt] = *(const h8*)(Xh + (size_t)node * 128 + koff);
        }
#pragma unroll
        for (int nt = 0; nt < 4; ++nt)
#pragma unroll
            for (int i = 0; i < 4; ++i)
                acc[nt][i] = __builtin_amdgcn_mfma_f32_16x16x32_f16(a[i], b[nt], acc[nt][i], 0, 0, 0);
    }

#pragma unroll
    for (int nt = 0; nt < 4; ++nt) {
        int node = ntile + nt * 16 + m16;
        if (node < n) {
#pragma unroll
            for (int i = 0; i < 4; ++i) {
                int ob = i * 16 + quad * 4;
                f4 v = acc[nt][i];
                if (ks == 0) {
                    const f4 b4 = *(const f4*)(bias + ob);
                    v += b4;
                }
                half4 h;
                h.x = (half1)v[0]; h.y = (half1)v[1]; h.z = (half1)v[2]; h.w = (half1)v[3];
                *(half4*)(CB + ((size_t)ks * n + node) * 64 + ob) = h;
            }
        }
    }
}

// ---------------- small-layer GEMM: block = KK waves, wave k, lane = node -------------
template <int KK, int DIN4, int NACC>
__global__ void gemm_smallw_kernel(const float* __restrict__ X, const float* __restrict__ Wp,
                                   const float* __restrict__ bias, int dout,
                                   half4* __restrict__ CB, int n) {
    int lane = threadIdx.x & 63;
    int k = __builtin_amdgcn_readfirstlane((int)(threadIdx.x >> 6));
    int node0 = blockIdx.x * 64 + lane;
    int node = min(node0, n - 1);
    f4 acc[NACC];
#pragma unroll
    for (int i = 0; i < NACC; ++i) {
        f4 v = {0.f, 0.f, 0.f, 0.f};
        if (k == 0 && bias) {
#pragma unroll
            for (int c = 0; c < 4; ++c) {
                int o = i * 4 + c;
                v[c] = (o < dout) ? bias[o] : 0.f;
            }
        }
        acc[i] = v;
    }
    const f4* Xr = (const f4*)(X + (size_t)node * (DIN4 * 4));
    const f4* Wk = (const f4*)(Wp + (size_t)k * (DIN4 * 4) * (NACC * 4));
    for (int d4 = 0; d4 < DIN4; ++d4) {
        f4 xv = Xr[d4];
#pragma unroll
        for (int j = 0; j < 4; ++j) {
            float xs = xv[j];
#pragma unroll
            for (int i = 0; i < NACC; ++i)
                acc[i] += xs * Wk[(d4 * 4 + j) * NACC + i];
        }
    }
    if (node0 < n) {
        size_t base = ((size_t)k * n + node) * NACC;
#pragma unroll
        for (int i = 0; i < NACC; ++i) {
            half4 h;
            h.x = (half1)acc[i].x; h.y = (half1)acc[i].y;
            h.z = (half1)acc[i].z; h.w = (half1)acc[i].w;
            CB[base + i] = h;
        }
    }
}

// ---------------- host driver ----------------

extern "C" void kernel_launch(void* const* d_in, const int* in_sizes, int n_in,
                              void* d_out, int out_size, void* d_ws, size_t ws_size,
                              hipStream_t stream) {
    const float* x  = (const float*)d_in[0];
    const int*   ei = (const int*)d_in[1];
    const float* Wl[4] = {(const float*)d_in[2], (const float*)d_in[4],
                          (const float*)d_in[6], (const float*)d_in[8]};
    const float* bl[4] = {(const float*)d_in[3], (const float*)d_in[5],
                          (const float*)d_in[7], (const float*)d_in[9]};
    const float* bn[3][4];
    for (int l = 0; l < 3; ++l)
        for (int j = 0; j < 4; ++j)
            bn[l][j] = (const float*)d_in[10 + 4 * l + j];

    char* ws = (char*)d_ws;
    size_t off = 0;
    auto alloc = [&](size_t bytes) -> void* {
        void* p = (void*)(ws + off);
        off = (off + bytes + 255) & ~(size_t)255;
        return p;
    };
    int*   deg     = (int*)alloc(NN * 4);
    int*   row_ptr = (int*)alloc((NN + 1) * 4);
    int*   blks    = (int*)alloc(128 * 4);
    unsigned int* cw = (unsigned int*)alloc((size_t)NE * 4);
    half1* CB1h    = (half1*)alloc((size_t)8 * NN * 64 * 2);
    half1* CBsh    = (half1*)alloc((size_t)6 * NN * 20 * 2);
    half1* S0      = (half1*)alloc((size_t)NN * 64 * 2);
    half1* S1      = (half1*)alloc((size_t)NN * 64 * 2);
    half1* S2      = (half1*)alloc((size_t)NN * 64 * 2);
    float* H1f     = (float*)alloc((size_t)NN * 64 * 4);
    float* H2f     = (float*)alloc((size_t)NN * 20 * 4);
    float* H3f     = (float*)alloc((size_t)NN * 12 * 4);
    float* Wp2     = (float*)alloc((size_t)6 * 64 * 20 * 4);
    float* Wp3     = (float*)alloc((size_t)4 * 20 * 12 * 4);
    float* Wp4     = (float*)alloc((size_t)4 * 12 * 12 * 4);
    half1* Xh      = (half1*)alloc((size_t)NN * 128 * 2);
    half1* Wt1     = (half1*)alloc((size_t)512 * 128 * 2);

    // scratch for CSR build, aliased into CB1h (consumed before gemm_mfma writes it):
    int2* tmp    = (int2*)CB1h;                             // 12.8 MB
    int*  hist_g = (int*)((char*)CB1h + (16u << 20));       // NC*NBUCK*4 = 600 KB
    int*  off_g  = hist_g + NC * NBUCK;                     // 600 KB

    const int* srcp = ei;
    const int* dstp = ei + NE;
    const int nscan = divup(NN, 1024);
    const int NB = divup(NN, 64);

    hipMemsetAsync(deg, 0, NN * 4, stream);
    hist2_kernel<<<NC, 256, 0, stream>>>(dstp, deg, hist_g);
    blksum_kernel<<<nscan, 256, 0, stream>>>(deg, blks, NN);
    blkscan_kernel<<<1, 256, 0, stream>>>(blks, nscan, row_ptr, NN);
    emit_kernel<<<nscan, 256, 0, stream>>>(deg, blks, row_ptr, NN);
    bucketoff_kernel<<<divup(NBUCK, 256), 256, 0, stream>>>(row_ptr, hist_g, off_g);
    binscatter_kernel<<<NC * 8, 256, 0, stream>>>(srcp, dstp, deg, off_g, tmp);
    finalize_kernel<<<NBUCK, 256, 0, stream>>>(tmp, row_ptr, cw);

    cvtx_kernel<<<divup(NN * 32, 256), 256, 0, stream>>>((const float4*)x, (half4*)Xh, NN * 32);
    transw_kernel<<<divup(512 * 128, 256), 256, 0, stream>>>(Wl[0], Wt1);
    padw_kernel<<<divup(6 * 64 * 20, 256), 256, 0, stream>>>(Wl[1], Wp2, 6, 64, 18, 64, 20);
    padw_kernel<<<divup(4 * 20 * 12, 256), 256, 0, stream>>>(Wl[2], Wp3, 4, 18, 9, 20, 12);
    padw_kernel<<<divup(4 * 12 * 12, 256), 256, 0, stream>>>(Wl[3], Wp4, 4, 9, 10, 12, 12);

    // dim-64 prop (h8 gathers)
    auto prop1 = [&](const half1* feat, const half1* sub, const half1* add,
                     half1* outh, float* outf, float scale, int bnrelu,
                     const float* g, const float* bb, const float* m, const float* v) {
        proph8_kernel<<<divup(NN * 8, 256), 256, 0, stream>>>(
            (const h8*)feat, (const h8*)sub, (const h8*)add,
            (h8*)outh, (f8*)outf, row_ptr, cw, NN, scale,
            sub != nullptr, bnrelu, g, bb, m, v);
    };
    // small-dim prop (half4 gathers)
    auto prop = [&](const half1* feat, const half1* sub, const half1* add,
                    half1* outh, float* outf, int dim4, float scale,
                    int bnrelu, int used, const float* g, const float* bb,
                    const float* m, const float* v) {
        proph_kernel<<<divup(NN * dim4, 256), 256, 0, stream>>>(
            (const half4*)feat, (const half4*)sub, (const half4*)add,
            (half4*)outh, (f4*)outf, row_ptr, cw, NN, dim4, scale,
            sub != nullptr, bnrelu, used, g, bb, m, v);
    };

    // ---- layer 1 (din=128, dout=64, K=8) -> H1f ----
    gemm_mfma_kernel<<<dim3(NB, 2), 256, 0, stream>>>(Xh, Wt1, bl[0], CB1h, NN);
    {
        auto C = [&](int k) { return (const half1*)(CB1h + (size_t)k * NN * 64); };
        prop1(C(7), nullptr, C(6), S0, nullptr, 2.f, 0, 0, 0, 0, 0);
        prop1(S0, C(7), C(5), S1, nullptr, 2.f, 0, 0, 0, 0, 0);
        prop1(S1, S0, C(4), S2, nullptr, 2.f, 0, 0, 0, 0, 0);
        prop1(S2, S1, C(3), S0, nullptr, 2.f, 0, 0, 0, 0, 0);
        prop1(S0, S2, C(2), S1, nullptr, 2.f, 0, 0, 0, 0, 0);
        prop1(S1, S0, C(1), S2, nullptr, 2.f, 0, 0, 0, 0, 0);
        prop1(S2, S1, C(0), nullptr, H1f, 1.f, 1,
              bn[0][0], bn[0][1], bn[0][2], bn[0][3]);
    }

    // ---- layer 2 (din=64, dout=18 pad 20, K=6): X=H1f -> H2f ----
    gemm_smallw_kernel<6, 16, 5><<<NB, 384, 0, stream>>>(H1f, Wp2, bl[1], 18,
                                                         (half4*)CBsh, NN);
    {
        auto C = [&](int k) { return (const half1*)(CBsh + (size_t)k * NN * 20); };
        prop(C(5), nullptr, C(4), S0, nullptr, 5, 2.f, 0, 18, 0, 0, 0, 0);
        prop(S0, C(5), C(3), S1, nullptr, 5, 2.f, 0, 18, 0, 0, 0, 0);
        prop(S1, S0, C(2), S2, nullptr, 5, 2.f, 0, 18, 0, 0, 0, 0);
        prop(S2, S1, C(1), S0, nullptr, 5, 2.f, 0, 18, 0, 0, 0, 0);
        prop(S0, S2, C(0), nullptr, H2f, 5, 1.f, 1, 18,
             bn[1][0], bn[1][1], bn[1][2], bn[1][3]);
    }

    // ---- layer 3 (din=18 str20, dout=9 pad 12, K=4): X=H2f -> H3f ----
    gemm_smallw_kernel<4, 5, 3><<<NB, 256, 0, stream>>>(H2f, Wp3, bl[2], 9,
                                                        (half4*)CBsh, NN);
    {
        auto C = [&](int k) { return (const half1*)(CBsh + (size_t)k * NN * 12); };
        prop(C(3), nullptr, C(2), S0, nullptr, 3, 2.f, 0, 9, 0, 0, 0, 0);
        prop(S0, C(3), C(1), S1, nullptr, 3, 2.f, 0, 9, 0, 0, 0, 0);
        prop(S1, S0, C(0), nullptr, H3f, 3, 1.f, 1, 9,
             bn[2][0], bn[2][1], bn[2][2], bn[2][3]);
    }

    // ---- layer 4 (din=9 str12, dout=10 pad 12, K=4): X=H3f -> d_out ----
    gemm_smallw_kernel<4, 3, 3><<<NB, 256, 0, stream>>>(H3f, Wp4, bl[3], 10,
                                                        (half4*)CBsh, NN);
    {
        auto C = [&](int k) { return (const half1*)(CBsh + (size_t)k * NN * 12); };
        prop(C(3), nullptr, C(2), S0, nullptr, 3, 2.f, 0, 10, 0, 0, 0, 0);
        prop(S0, C(3), C(1), S1, nullptr, 3, 2.f, 0, 10, 0, 0, 0, 0);
        propl_kernel<<<divup(NN * 3, 256), 256, 0, stream>>>(
            (const half4*)S1, (const half4*)S0, (const half4*)CBsh,
            (float*)d_out, row_ptr, cw, NN);
    }
}

// Round 3
// 824.981 us; speedup vs baseline: 1.0708x; 1.0379x over previous
//
#include <hip/hip_runtime.h>

#define NN 100000
#define NE 1600000
#define BN_EPS 1e-5f

// CSR binning parameters
#define BSH 7
#define BSZ (1 << BSH)   // 128 dsts per bucket
#define NBUCK 782        // divup(NN, BSZ)
#define NC 192           // edge chunks
#define CE 8334          // divup(NE, NC)

typedef _Float16 half1;
typedef _Float16 half4 __attribute__((ext_vector_type(4)));
typedef _Float16 h8 __attribute__((ext_vector_type(8)));
typedef float f4 __attribute__((ext_vector_type(4)));
typedef float f8 __attribute__((ext_vector_type(8)));

static inline int divup(int a, int b) { return (a + b - 1) / b; }

// per-edge source weight from packed entry: src in [0:17), deg_src in [17:32)
__device__ __forceinline__ float wsrc(unsigned int q) {
    unsigned int dg = q >> 17;
    return dg ? rsqrtf((float)dg) : 0.f;
}

// ---------------- preprocessing (no global atomics) ----------------

// per-chunk bucket histogram, LDS only
__global__ void histb_kernel(const int* __restrict__ dst, int* __restrict__ hist_g) {
    __shared__ int h[NBUCK];
    int c = blockIdx.x;
    for (int i = threadIdx.x; i < NBUCK; i += blockDim.x) h[i] = 0;
    __syncthreads();
    int e0 = c * CE, e1 = min(e0 + CE, NE);
    for (int e = e0 + threadIdx.x; e < e1; e += blockDim.x)
        atomicAdd(&h[dst[e] >> BSH], 1);
    __syncthreads();
    for (int i = threadIdx.x; i < NBUCK; i += blockDim.x) hist_g[c * NBUCK + i] = h[i];
}

// single block: bucket totals + exclusive scan -> bucket_start[0..NBUCK]
__global__ void bscan1_kernel(const int* __restrict__ hist_g, int* __restrict__ bucket_start,
                              int* __restrict__ row_ptr) {
    __shared__ int sh[1024];
    int t = threadIdx.x;
    int tot = 0;
    if (t < NBUCK)
        for (int c = 0; c < NC; ++c) tot += hist_g[c * NBUCK + t];
    sh[t] = (t < NBUCK) ? tot : 0;
    __syncthreads();
    for (int off = 1; off < 1024; off <<= 1) {
        int v = (t >= off) ? sh[t - off] : 0;
        __syncthreads();
        sh[t] += v;
        __syncthreads();
    }
    if (t < NBUCK) bucket_start[t] = sh[t] - tot;
    if (t == 0) { bucket_start[NBUCK] = NE; row_ptr[NN] = NE; }
}

// off_g[c][b] = bucket_start[b] + prefix over chunks
__global__ void boff_kernel(const int* __restrict__ bucket_start, const int* __restrict__ hist_g,
                            int* __restrict__ off_g) {
    int b = blockIdx.x * blockDim.x + threadIdx.x;
    if (b >= NBUCK) return;
    int run = bucket_start[b];
#pragma unroll 4
    for (int c = 0; c < NC; ++c) {
        off_g[c * NBUCK + b] = run;
        run += hist_g[c * NBUCK + b];
    }
}

// XCD-pinned bucket scatter: 4B packed tmp entries (src | local_d<<25)
__global__ void binscatter_kernel(const int* __restrict__ src, const int* __restrict__ dst,
                                  const int* __restrict__ off_g, unsigned int* __restrict__ tmp) {
    __shared__ int off_l[NBUCK];
    int myx = blockIdx.x & 7;
    int c = blockIdx.x >> 3;
    for (int i = threadIdx.x; i < NBUCK; i += blockDim.x)
        off_l[i] = ((i & 7) == myx) ? off_g[c * NBUCK + i] : 0;
    __syncthreads();
    int e0 = c * CE, e1 = min(e0 + CE, NE);
    for (int e = e0 + threadIdx.x; e < e1; e += blockDim.x) {
        int d = dst[e];
        int b = d >> BSH;
        if ((b & 7) != myx) continue;
        int s = src[e];
        int pos = atomicAdd(&off_l[b], 1);
        tmp[pos] = (unsigned int)s | ((unsigned int)(d & (BSZ - 1)) << 25);
    }
}

// per-bucket: LDS degree count + scan -> deg, row_ptr, CSR placement (src-only cw)
__global__ void finalize_kernel(const unsigned int* __restrict__ tmp,
                                const int* __restrict__ bucket_start,
                                int* __restrict__ row_ptr, int* __restrict__ deg,
                                unsigned int* __restrict__ cw) {
    __shared__ int cnt[BSZ], sc[BSZ], cur[BSZ];
    int b = blockIdx.x, t = threadIdx.x;
    int e0 = bucket_start[b], e1 = bucket_start[b + 1];
    if (t < BSZ) cnt[t] = 0;
    __syncthreads();
    for (int e = e0 + t; e < e1; e += blockDim.x) atomicAdd(&cnt[tmp[e] >> 25], 1);
    __syncthreads();
    if (t < BSZ) sc[t] = cnt[t];
    __syncthreads();
    for (int off = 1; off < BSZ; off <<= 1) {
        int v = (t >= off && t < BSZ) ? sc[t - off] : 0;
        __syncthreads();
        if (t < BSZ) sc[t] += v;
        __syncthreads();
    }
    if (t < BSZ) {
        int p = e0 + sc[t] - cnt[t];
        cur[t] = p;
        int nd = (b << BSH) + t;
        if (nd < NN) { row_ptr[nd] = p; deg[nd] = cnt[t]; }
    }
    __syncthreads();
    for (int e = e0 + t; e < e1; e += blockDim.x) {
        unsigned int r = tmp[e];
        int ld = r >> 25;
        int k = atomicAdd(&cur[ld], 1);
        cw[k] = r & 0x1FFFFu;
    }
}

// OR deg[src] bits into cw entries
__global__ void packdeg_kernel(unsigned int* __restrict__ cw, const int* __restrict__ deg) {
    int e = blockIdx.x * blockDim.x + threadIdx.x;
    if (e >= NE) return;
    unsigned int q = cw[e];
    int dg = deg[q];
    if (dg > 32767) dg = 32767;
    cw[e] = q | ((unsigned int)dg << 17);
}

// ---------------- fp16 converts for MFMA ----------------

__global__ void cvtx_kernel(const float4* __restrict__ X, half4* __restrict__ Xh, int tot4) {
    int i = blockIdx.x * blockDim.x + threadIdx.x;
    if (i >= tot4) return;
    float4 v = X[i];
    half4 h;
    h.x = (half1)v.x; h.y = (half1)v.y; h.z = (half1)v.z; h.w = (half1)v.w;
    Xh[i] = h;
}

// Wt[og][kd] = W1[og>>6][kd][og&63], fp16 ; Wt is [512][128]
__global__ void transw_kernel(const float* __restrict__ W, half1* __restrict__ Wt) {
    int i = blockIdx.x * blockDim.x + threadIdx.x;
    if (i >= 512 * 128) return;
    int kd = i >> 9;
    int og = i & 511;
    int k = og >> 6, o = og & 63;
    Wt[(size_t)og * 128 + kd] = (half1)W[((size_t)k * 128 + kd) * 64 + o];
}

// ---------------- W padding ----------------
__global__ void padw_kernel(const float* __restrict__ src, float* __restrict__ dst,
                            int K, int dins, int douts, int dind, int doutd) {
    int i = blockIdx.x * blockDim.x + threadIdx.x;
    int tot = K * dind * doutd;
    if (i >= tot) return;
    int o = i % doutd;
    int r = i / doutd;
    int dd = r % dind;
    int k = r / dind;
    dst[i] = (dd < dins && o < douts) ? src[((size_t)k * dins + dd) * douts + o] : 0.f;
}

// ---------------- Clenshaw prop, h8 (16B) gathers — dim == 64 ----------------
__global__ void proph8_kernel(const h8* __restrict__ feat, const h8* __restrict__ sub,
                              const h8* __restrict__ add, h8* __restrict__ outh,
                              f8* __restrict__ outf,
                              const int* __restrict__ row_ptr, const unsigned int* __restrict__ cw,
                              int n, float scale, int has_sub, int bnrelu,
                              const float* __restrict__ bn_g, const float* __restrict__ bn_b,
                              const float* __restrict__ bn_m, const float* __restrict__ bn_v) {
    int idx = blockIdx.x * blockDim.x + threadIdx.x;
    if (idx >= n * 8) return;
    int nd = idx >> 3;
    int f = idx & 7;
    int e0 = row_ptr[nd], e1 = row_ptr[nd + 1];
    f8 a0 = {0.f, 0.f, 0.f, 0.f, 0.f, 0.f, 0.f, 0.f}, a1 = a0, a2 = a0, a3 = a0;
    int e = e0;
    for (; e + 8 <= e1; e += 8) {
        unsigned int q0 = cw[e], q1 = cw[e + 1], q2 = cw[e + 2], q3 = cw[e + 3];
        unsigned int q4 = cw[e + 4], q5 = cw[e + 5], q6 = cw[e + 6], q7 = cw[e + 7];
        f8 v0 = __builtin_convertvector(feat[(size_t)(q0 & 0x1FFFFu) * 8 + f], f8);
        f8 v1 = __builtin_convertvector(feat[(size_t)(q1 & 0x1FFFFu) * 8 + f], f8);
        f8 v2 = __builtin_convertvector(feat[(size_t)(q2 & 0x1FFFFu) * 8 + f], f8);
        f8 v3 = __builtin_convertvector(feat[(size_t)(q3 & 0x1FFFFu) * 8 + f], f8);
        f8 v4 = __builtin_convertvector(feat[(size_t)(q4 & 0x1FFFFu) * 8 + f], f8);
        f8 v5 = __builtin_convertvector(feat[(size_t)(q5 & 0x1FFFFu) * 8 + f], f8);
        f8 v6 = __builtin_convertvector(feat[(size_t)(q6 & 0x1FFFFu) * 8 + f], f8);
        f8 v7 = __builtin_convertvector(feat[(size_t)(q7 & 0x1FFFFu) * 8 + f], f8);
        a0 += wsrc(q0) * v0;
        a1 += wsrc(q1) * v1;
        a2 += wsrc(q2) * v2;
        a3 += wsrc(q3) * v3;
        a0 += wsrc(q4) * v4;
        a1 += wsrc(q5) * v5;
        a2 += wsrc(q6) * v6;
        a3 += wsrc(q7) * v7;
    }
    for (; e + 4 <= e1; e += 4) {
        unsigned int q0 = cw[e], q1 = cw[e + 1], q2 = cw[e + 2], q3 = cw[e + 3];
        f8 v0 = __builtin_convertvector(feat[(size_t)(q0 & 0x1FFFFu) * 8 + f], f8);
        f8 v1 = __builtin_convertvector(feat[(size_t)(q1 & 0x1FFFFu) * 8 + f], f8);
        f8 v2 = __builtin_convertvector(feat[(size_t)(q2 & 0x1FFFFu) * 8 + f], f8);
        f8 v3 = __builtin_convertvector(feat[(size_t)(q3 & 0x1FFFFu) * 8 + f], f8);
        a0 += wsrc(q0) * v0;
        a1 += wsrc(q1) * v1;
        a2 += wsrc(q2) * v2;
        a3 += wsrc(q3) * v3;
    }
    for (; e < e1; ++e) {
        unsigned int q = cw[e];
        a0 += wsrc(q) * __builtin_convertvector(feat[(size_t)(q & 0x1FFFFu) * 8 + f], f8);
    }
    int degd = e1 - e0;
    float ms = (degd > 0) ? -scale * rsqrtf((float)degd) : 0.f;
    f8 r = ((a0 + a1) + (a2 + a3)) * ms;
    if (has_sub) r -= __builtin_convertvector(sub[idx], f8);
    r += __builtin_convertvector(__builtin_nontemporal_load(&add[idx]), f8);
    if (bnrelu) {
#pragma unroll
        for (int c = 0; c < 8; ++c) {
            int o = f * 8 + c;
            float sc = bn_g[o] * rsqrtf(bn_v[o] + BN_EPS);
            r[c] = fmaxf(fmaf(r[c] - bn_m[o], sc, bn_b[o]), 0.f);
        }
    }
    if (outf) {
        outf[idx] = r;
    } else {
        outh[idx] = __builtin_convertvector(r, h8);
    }
}

// ---------------- Clenshaw prop, half4 gathers — small dims ----------------
__global__ void proph_kernel(const half4* __restrict__ feat, const half4* __restrict__ sub,
                             const half4* __restrict__ add, half4* __restrict__ outh,
                             f4* __restrict__ outf,
                             const int* __restrict__ row_ptr, const unsigned int* __restrict__ cw,
                             int n, int dim4, float scale, int has_sub,
                             int bnrelu, int used,
                             const float* __restrict__ bn_g, const float* __restrict__ bn_b,
                             const float* __restrict__ bn_m, const float* __restrict__ bn_v) {
    int idx = blockIdx.x * blockDim.x + threadIdx.x;
    if (idx >= n * dim4) return;
    int nd = idx / dim4;
    int f = idx - nd * dim4;
    int e0 = row_ptr[nd], e1 = row_ptr[nd + 1];
    f4 a0 = {0.f, 0.f, 0.f, 0.f}, a1 = a0, a2 = a0, a3 = a0;
    int e = e0;
    for (; e + 4 <= e1; e += 4) {
        unsigned int q0 = cw[e], q1 = cw[e + 1], q2 = cw[e + 2], q3 = cw[e + 3];
        f4 v0 = __builtin_convertvector(feat[(size_t)(q0 & 0x1FFFFu) * dim4 + f], f4);
        f4 v1 = __builtin_convertvector(feat[(size_t)(q1 & 0x1FFFFu) * dim4 + f], f4);
        f4 v2 = __builtin_convertvector(feat[(size_t)(q2 & 0x1FFFFu) * dim4 + f], f4);
        f4 v3 = __builtin_convertvector(feat[(size_t)(q3 & 0x1FFFFu) * dim4 + f], f4);
        a0 += wsrc(q0) * v0;
        a1 += wsrc(q1) * v1;
        a2 += wsrc(q2) * v2;
        a3 += wsrc(q3) * v3;
    }
    for (; e < e1; ++e) {
        unsigned int q = cw[e];
        a0 += wsrc(q) * __builtin_convertvector(feat[(size_t)(q & 0x1FFFFu) * dim4 + f], f4);
    }
    int degd = e1 - e0;
    float ms = (degd > 0) ? -scale * rsqrtf((float)degd) : 0.f;
    f4 r = ((a0 + a1) + (a2 + a3)) * ms;
    if (has_sub) r -= __builtin_convertvector(sub[idx], f4);
    r += __builtin_convertvector(__builtin_nontemporal_load(&add[idx]), f4);
    if (bnrelu) {
#pragma unroll
        for (int c = 0; c < 4; ++c) {
            int o = f * 4 + c;
            if (o < used) {
                float sc = bn_g[o] * rsqrtf(bn_v[o] + BN_EPS);
                r[c] = fmaxf(fmaf(r[c] - bn_m[o], sc, bn_b[o]), 0.f);
            } else r[c] = 0.f;
        }
    }
    if (outf) {
        outf[idx] = r;
    } else {
        half4 h;
        h.x = (half1)r.x; h.y = (half1)r.y; h.z = (half1)r.z; h.w = (half1)r.w;
        outh[idx] = h;
    }
}

// layer-4 final: fp16 gathers/streams at stride 12 (dim4=3), fp32 out at stride 10
__global__ void propl_kernel(const half4* __restrict__ feat, const half4* __restrict__ sub,
                             const half4* __restrict__ add, float* __restrict__ out,
                             const int* __restrict__ row_ptr, const unsigned int* __restrict__ cw,
                             int n) {
    int idx = blockIdx.x * blockDim.x + threadIdx.x;
    if (idx >= n * 3) return;
    int nd = idx / 3;
    int f = idx - nd * 3;
    int e0 = row_ptr[nd], e1 = row_ptr[nd + 1];
    f4 a0 = {0.f, 0.f, 0.f, 0.f}, a1 = a0, a2 = a0, a3 = a0;
    int e = e0;
    for (; e + 4 <= e1; e += 4) {
        unsigned int q0 = cw[e], q1 = cw[e + 1], q2 = cw[e + 2], q3 = cw[e + 3];
        a0 += wsrc(q0) * __builtin_convertvector(feat[(size_t)(q0 & 0x1FFFFu) * 3 + f], f4);
        a1 += wsrc(q1) * __builtin_convertvector(feat[(size_t)(q1 & 0x1FFFFu) * 3 + f], f4);
        a2 += wsrc(q2) * __builtin_convertvector(feat[(size_t)(q2 & 0x1FFFFu) * 3 + f], f4);
        a3 += wsrc(q3) * __builtin_convertvector(feat[(size_t)(q3 & 0x1FFFFu) * 3 + f], f4);
    }
    for (; e < e1; ++e) {
        unsigned int q = cw[e];
        a0 += wsrc(q) * __builtin_convertvector(feat[(size_t)(q & 0x1FFFFu) * 3 + f], f4);
    }
    int degd = e1 - e0;
    float ms = (degd > 0) ? -rsqrtf((float)degd) : 0.f;
    f4 r = ((a0 + a1) + (a2 + a3)) * ms;
    r -= __builtin_convertvector(sub[idx], f4);
    r += __builtin_convertvector(add[idx], f4);
    int o = f * 4;
    float* orow = out + (size_t)nd * 10;
    if (o + 0 < 10) orow[o + 0] = r.x;
    if (o + 1 < 10) orow[o + 1] = r.y;
    if (o + 2 < 10) orow[o + 2] = r.z;
    if (o + 3 < 10) orow[o + 3] = r.w;
}

// ---------------- layer-1 GEMM via MFMA (8 waves = 8 k-slices per block) ----------------
__global__ __launch_bounds__(512) void gemm_mfma_kernel(
        const half1* __restrict__ Xh, const half1* __restrict__ Wt,
        const float* __restrict__ bias, half1* __restrict__ CB, int n) {
    int lane = threadIdx.x & 63;
    int ks = threadIdx.x >> 6;   // 0..7
    int m16 = lane & 15;
    int quad = lane >> 4;
    int ntile = blockIdx.x * 64;

    f4 acc[4][4];
#pragma unroll
    for (int nt = 0; nt < 4; ++nt)
#pragma unroll
        for (int i = 0; i < 4; ++i) acc[nt][i] = (f4){0.f, 0.f, 0.f, 0.f};

#pragma unroll
    for (int kc = 0; kc < 4; ++kc) {
        int koff = kc * 32 + quad * 8;
        h8 a[4];
#pragma unroll
        for (int i = 0; i < 4; ++i)
            a[i] = *(const h8*)(Wt + (size_t)(ks * 64 + i * 16 + m16) * 128 + koff);
        h8 b[4];
#pragma unroll
        for (int nt = 0; nt < 4; ++nt) {
            int node = min(ntile + nt * 16 + m16, n - 1);
            b[nt] = *(const h8*)(Xh + (size_t)node * 128 + koff);
        }
#pragma unroll
        for (int nt = 0; nt < 4; ++nt)
#pragma unroll
            for (int i = 0; i < 4; ++i)
                acc[nt][i] = __builtin_amdgcn_mfma_f32_16x16x32_f16(a[i], b[nt], acc[nt][i], 0, 0, 0);
    }

#pragma unroll
    for (int nt = 0; nt < 4; ++nt) {
        int node = ntile + nt * 16 + m16;
        if (node < n) {
#pragma unroll
            for (int i = 0; i < 4; ++i) {
                int ob = i * 16 + quad * 4;
                f4 v = acc[nt][i];
                if (ks == 0) {
                    const f4 b4 = *(const f4*)(bias + ob);
                    v += b4;
                }
                half4 h;
                h.x = (half1)v[0]; h.y = (half1)v[1]; h.z = (half1)v[2]; h.w = (half1)v[3];
                __builtin_nontemporal_store(h, (half4*)(CB + ((size_t)ks * n + node) * 64 + ob));
            }
        }
    }
}

// ---------------- small-layer GEMM: block = KK waves, wave k, lane = node -------------
template <int KK, int DIN4, int NACC>
__global__ void gemm_smallw_kernel(const float* __restrict__ X, const float* __restrict__ Wp,
                                   const float* __restrict__ bias, int dout,
                                   half4* __restrict__ CB, int n) {
    int lane = threadIdx.x & 63;
    int k = __builtin_amdgcn_readfirstlane((int)(threadIdx.x >> 6));
    int node0 = blockIdx.x * 64 + lane;
    int node = min(node0, n - 1);
    f4 acc[NACC];
#pragma unroll
    for (int i = 0; i < NACC; ++i) {
        f4 v = {0.f, 0.f, 0.f, 0.f};
        if (k == 0 && bias) {
#pragma unroll
            for (int c = 0; c < 4; ++c) {
                int o = i * 4 + c;
                v[c] = (o < dout) ? bias[o] : 0.f;
            }
        }
        acc[i] = v;
    }
    const f4* Xr = (const f4*)(X + (size_t)node * (DIN4 * 4));
    const f4* Wk = (const f4*)(Wp + (size_t)k * (DIN4 * 4) * (NACC * 4));
    for (int d4 = 0; d4 < DIN4; ++d4) {
        f4 xv = Xr[d4];
#pragma unroll
        for (int j = 0; j < 4; ++j) {
            float xs = xv[j];
#pragma unroll
            for (int i = 0; i < NACC; ++i)
                acc[i] += xs * Wk[(d4 * 4 + j) * NACC + i];
        }
    }
    if (node0 < n) {
        size_t base = ((size_t)k * n + node) * NACC;
#pragma unroll
        for (int i = 0; i < NACC; ++i) {
            half4 h;
            h.x = (half1)acc[i].x; h.y = (half1)acc[i].y;
            h.z = (half1)acc[i].z; h.w = (half1)acc[i].w;
            CB[base + i] = h;
        }
    }
}

// ---------------- host driver ----------------

extern "C" void kernel_launch(void* const* d_in, const int* in_sizes, int n_in,
                              void* d_out, int out_size, void* d_ws, size_t ws_size,
                              hipStream_t stream) {
    const float* x  = (const float*)d_in[0];
    const int*   ei = (const int*)d_in[1];
    const float* Wl[4] = {(const float*)d_in[2], (const float*)d_in[4],
                          (const float*)d_in[6], (const float*)d_in[8]};
    const float* bl[4] = {(const float*)d_in[3], (const float*)d_in[5],
                          (const float*)d_in[7], (const float*)d_in[9]};
    const float* bn[3][4];
    for (int l = 0; l < 3; ++l)
        for (int j = 0; j < 4; ++j)
            bn[l][j] = (const float*)d_in[10 + 4 * l + j];

    char* ws = (char*)d_ws;
    size_t off = 0;
    auto alloc = [&](size_t bytes) -> void* {
        void* p = (void*)(ws + off);
        off = (off + bytes + 255) & ~(size_t)255;
        return p;
    };
    int*   deg      = (int*)alloc(NN * 4);
    int*   row_ptr  = (int*)alloc((NN + 1) * 4);
    int*   bstart   = (int*)alloc((NBUCK + 1) * 4);
    unsigned int* cw = (unsigned int*)alloc((size_t)NE * 4);
    half1* CB1h    = (half1*)alloc((size_t)8 * NN * 64 * 2);
    half1* CBsh    = (half1*)alloc((size_t)6 * NN * 20 * 2);
    half1* S0      = (half1*)alloc((size_t)NN * 64 * 2);
    half1* S1      = (half1*)alloc((size_t)NN * 64 * 2);
    half1* S2      = (half1*)alloc((size_t)NN * 64 * 2);
    float* H1f     = (float*)alloc((size_t)NN * 64 * 4);
    float* H2f     = (float*)alloc((size_t)NN * 20 * 4);
    float* H3f     = (float*)alloc((size_t)NN * 12 * 4);
    float* Wp2     = (float*)alloc((size_t)6 * 64 * 20 * 4);
    float* Wp3     = (float*)alloc((size_t)4 * 20 * 12 * 4);
    float* Wp4     = (float*)alloc((size_t)4 * 12 * 12 * 4);
    half1* Xh      = (half1*)alloc((size_t)NN * 128 * 2);
    half1* Wt1     = (half1*)alloc((size_t)512 * 128 * 2);

    // CSR-build scratch aliased into CB1h (consumed before gemm_mfma writes it):
    unsigned int* tmp = (unsigned int*)CB1h;                // 6.4 MB
    int* hist_g = (int*)((char*)CB1h + (16u << 20));        // NC*NBUCK*4 = 600 KB
    int* off_g  = hist_g + NC * NBUCK;                      // 600 KB

    const int* srcp = ei;
    const int* dstp = ei + NE;
    const int NB = divup(NN, 64);

    histb_kernel<<<NC, 256, 0, stream>>>(dstp, hist_g);
    bscan1_kernel<<<1, 1024, 0, stream>>>(hist_g, bstart, row_ptr);
    boff_kernel<<<divup(NBUCK, 256), 256, 0, stream>>>(bstart, hist_g, off_g);
    binscatter_kernel<<<NC * 8, 256, 0, stream>>>(srcp, dstp, off_g, tmp);
    finalize_kernel<<<NBUCK, 256, 0, stream>>>(tmp, bstart, row_ptr, deg, cw);
    packdeg_kernel<<<divup(NE, 256), 256, 0, stream>>>(cw, deg);

    cvtx_kernel<<<divup(NN * 32, 256), 256, 0, stream>>>((const float4*)x, (half4*)Xh, NN * 32);
    transw_kernel<<<divup(512 * 128, 256), 256, 0, stream>>>(Wl[0], Wt1);
    padw_kernel<<<divup(6 * 64 * 20, 256), 256, 0, stream>>>(Wl[1], Wp2, 6, 64, 18, 64, 20);
    padw_kernel<<<divup(4 * 20 * 12, 256), 256, 0, stream>>>(Wl[2], Wp3, 4, 18, 9, 20, 12);
    padw_kernel<<<divup(4 * 12 * 12, 256), 256, 0, stream>>>(Wl[3], Wp4, 4, 9, 10, 12, 12);

    // dim-64 prop (h8 gathers)
    auto prop1 = [&](const half1* feat, const half1* sub, const half1* add,
                     half1* outh, float* outf, float scale, int bnrelu,
                     const float* g, const float* bb, const float* m, const float* v) {
        proph8_kernel<<<divup(NN * 8, 256), 256, 0, stream>>>(
            (const h8*)feat, (const h8*)sub, (const h8*)add,
            (h8*)outh, (f8*)outf, row_ptr, cw, NN, scale,
            sub != nullptr, bnrelu, g, bb, m, v);
    };
    // small-dim prop (half4 gathers)
    auto prop = [&](const half1* feat, const half1* sub, const half1* add,
                    half1* outh, float* outf, int dim4, float scale,
                    int bnrelu, int used, const float* g, const float* bb,
                    const float* m, const float* v) {
        proph_kernel<<<divup(NN * dim4, 256), 256, 0, stream>>>(
            (const half4*)feat, (const half4*)sub, (const half4*)add,
            (half4*)outh, (f4*)outf, row_ptr, cw, NN, dim4, scale,
            sub != nullptr, bnrelu, used, g, bb, m, v);
    };

    // ---- layer 1 (din=128, dout=64, K=8) -> H1f ----
    gemm_mfma_kernel<<<NB, 512, 0, stream>>>(Xh, Wt1, bl[0], CB1h, NN);
    {
        auto C = [&](int k) { return (const half1*)(CB1h + (size_t)k * NN * 64); };
        prop1(C(7), nullptr, C(6), S0, nullptr, 2.f, 0, 0, 0, 0, 0);
        prop1(S0, C(7), C(5), S1, nullptr, 2.f, 0, 0, 0, 0, 0);
        prop1(S1, S0, C(4), S2, nullptr, 2.f, 0, 0, 0, 0, 0);
        prop1(S2, S1, C(3), S0, nullptr, 2.f, 0, 0, 0, 0, 0);
        prop1(S0, S2, C(2), S1, nullptr, 2.f, 0, 0, 0, 0, 0);
        prop1(S1, S0, C(1), S2, nullptr, 2.f, 0, 0, 0, 0, 0);
        prop1(S2, S1, C(0), nullptr, H1f, 1.f, 1,
              bn[0][0], bn[0][1], bn[0][2], bn[0][3]);
    }

    // ---- layer 2 (din=64, dout=18 pad 20, K=6): X=H1f -> H2f ----
    gemm_smallw_kernel<6, 16, 5><<<NB, 384, 0, stream>>>(H1f, Wp2, bl[1], 18,
                                                         (half4*)CBsh, NN);
    {
        auto C = [&](int k) { return (const half1*)(CBsh + (size_t)k * NN * 20); };
        prop(C(5), nullptr, C(4), S0, nullptr, 5, 2.f, 0, 18, 0, 0, 0, 0);
        prop(S0, C(5), C(3), S1, nullptr, 5, 2.f, 0, 18, 0, 0, 0, 0);
        prop(S1, S0, C(2), S2, nullptr, 5, 2.f, 0, 18, 0, 0, 0, 0);
        prop(S2, S1, C(1), S0, nullptr, 5, 2.f, 0, 18, 0, 0, 0, 0);
        prop(S0, S2, C(0), nullptr, H2f, 5, 1.f, 1, 18,
             bn[1][0], bn[1][1], bn[1][2], bn[1][3]);
    }

    // ---- layer 3 (din=18 str20, dout=9 pad 12, K=4): X=H2f -> H3f ----
    gemm_smallw_kernel<4, 5, 3><<<NB, 256, 0, stream>>>(H2f, Wp3, bl[2], 9,
                                                        (half4*)CBsh, NN);
    {
        auto C = [&](int k) { return (const half1*)(CBsh + (size_t)k * NN * 12); };
        prop(C(3), nullptr, C(2), S0, nullptr, 3, 2.f, 0, 9, 0, 0, 0, 0);
        prop(S0, C(3), C(1), S1, nullptr, 3, 2.f, 0, 9, 0, 0, 0, 0);
        prop(S1, S0, C(0), nullptr, H3f, 3, 1.f, 1, 9,
             bn[2][0], bn[2][1], bn[2][2], bn[2][3]);
    }

    // ---- layer 4 (din=9 str12, dout=10 pad 12, K=4): X=H3f -> d_out ----
    gemm_smallw_kernel<4, 3, 3><<<NB, 256, 0, stream>>>(H3f, Wp4, bl[3], 10,
                                                        (half4*)CBsh, NN);
    {
        auto C = [&](int k) { return (const half1*)(CBsh + (size_t)k * NN * 12); };
        prop(C(3), nullptr, C(2), S0, nullptr, 3, 2.f, 0, 10, 0, 0, 0, 0);
        prop(S0, C(3), C(1), S1, nullptr, 3, 2.f, 0, 10, 0, 0, 0, 0);
        propl_kernel<<<divup(NN * 3, 256), 256, 0, stream>>>(
            (const half4*)S1, (const half4*)S0, (const half4*)CBsh,
            (float*)d_out, row_ptr, cw, NN);
    }
}

// Round 4
// 795.653 us; speedup vs baseline: 1.1102x; 1.0369x over previous
//
#include <hip/hip_runtime.h>

#define NN 100000
#define NE 1600000
#define BN_EPS 1e-5f

// CSR binning parameters
#define BSH 7
#define BSZ (1 << BSH)   // 128 dsts per bucket
#define NBUCK 782        // divup(NN, BSZ)
#define NC 192           // edge chunks
#define CE 8334          // divup(NE, NC)

typedef _Float16 half1;
typedef _Float16 half4 __attribute__((ext_vector_type(4)));
typedef _Float16 h8 __attribute__((ext_vector_type(8)));
typedef float f4 __attribute__((ext_vector_type(4)));
typedef float f8 __attribute__((ext_vector_type(8)));

static inline int divup(int a, int b) { return (a + b - 1) / b; }

// per-edge source weight from packed entry: src in [0:17), deg_src in [17:32)
__device__ __forceinline__ float wsrc(unsigned int q) {
    unsigned int dg = q >> 17;
    return dg ? rsqrtf((float)dg) : 0.f;
}

// ---------------- preprocessing (no global atomics) ----------------

// per-chunk bucket histogram, LDS only
__global__ void histb_kernel(const int* __restrict__ dst, int* __restrict__ hist_g) {
    __shared__ int h[NBUCK];
    int c = blockIdx.x;
    for (int i = threadIdx.x; i < NBUCK; i += blockDim.x) h[i] = 0;
    __syncthreads();
    int e0 = c * CE, e1 = min(e0 + CE, NE);
    for (int e = e0 + threadIdx.x; e < e1; e += blockDim.x)
        atomicAdd(&h[dst[e] >> BSH], 1);
    __syncthreads();
    for (int i = threadIdx.x; i < NBUCK; i += blockDim.x) hist_g[c * NBUCK + i] = h[i];
}

// single block: bucket totals + exclusive scan -> bucket_start[0..NBUCK]
__global__ void bscan1_kernel(const int* __restrict__ hist_g, int* __restrict__ bucket_start,
                              int* __restrict__ row_ptr) {
    __shared__ int sh[1024];
    int t = threadIdx.x;
    int tot = 0;
    if (t < NBUCK)
        for (int c = 0; c < NC; ++c) tot += hist_g[c * NBUCK + t];
    sh[t] = (t < NBUCK) ? tot : 0;
    __syncthreads();
    for (int off = 1; off < 1024; off <<= 1) {
        int v = (t >= off) ? sh[t - off] : 0;
        __syncthreads();
        sh[t] += v;
        __syncthreads();
    }
    if (t < NBUCK) bucket_start[t] = sh[t] - tot;
    if (t == 0) { bucket_start[NBUCK] = NE; row_ptr[NN] = NE; }
}

// off_g[c][b] = bucket_start[b] + prefix over chunks
__global__ void boff_kernel(const int* __restrict__ bucket_start, const int* __restrict__ hist_g,
                            int* __restrict__ off_g) {
    int b = blockIdx.x * blockDim.x + threadIdx.x;
    if (b >= NBUCK) return;
    int run = bucket_start[b];
#pragma unroll 4
    for (int c = 0; c < NC; ++c) {
        off_g[c * NBUCK + b] = run;
        run += hist_g[c * NBUCK + b];
    }
}

// XCD-pinned bucket scatter: 4B packed tmp entries (src | local_d<<25)
__global__ void binscatter_kernel(const int* __restrict__ src, const int* __restrict__ dst,
                                  const int* __restrict__ off_g, unsigned int* __restrict__ tmp) {
    __shared__ int off_l[NBUCK];
    int myx = blockIdx.x & 7;
    int c = blockIdx.x >> 3;
    for (int i = threadIdx.x; i < NBUCK; i += blockDim.x)
        off_l[i] = ((i & 7) == myx) ? off_g[c * NBUCK + i] : 0;
    __syncthreads();
    int e0 = c * CE, e1 = min(e0 + CE, NE);
    for (int e = e0 + threadIdx.x; e < e1; e += blockDim.x) {
        int d = dst[e];
        int b = d >> BSH;
        if ((b & 7) != myx) continue;
        int s = src[e];
        int pos = atomicAdd(&off_l[b], 1);
        tmp[pos] = (unsigned int)s | ((unsigned int)(d & (BSZ - 1)) << 25);
    }
}

// per-bucket: LDS degree count + scan -> deg, row_ptr, CSR placement (src-only cw)
__global__ void finalize_kernel(const unsigned int* __restrict__ tmp,
                                const int* __restrict__ bucket_start,
                                int* __restrict__ row_ptr, int* __restrict__ deg,
                                unsigned int* __restrict__ cw) {
    __shared__ int cnt[BSZ], sc[BSZ], cur[BSZ];
    int b = blockIdx.x, t = threadIdx.x;
    int e0 = bucket_start[b], e1 = bucket_start[b + 1];
    if (t < BSZ) cnt[t] = 0;
    __syncthreads();
    for (int e = e0 + t; e < e1; e += blockDim.x) atomicAdd(&cnt[tmp[e] >> 25], 1);
    __syncthreads();
    if (t < BSZ) sc[t] = cnt[t];
    __syncthreads();
    for (int off = 1; off < BSZ; off <<= 1) {
        int v = (t >= off && t < BSZ) ? sc[t - off] : 0;
        __syncthreads();
        if (t < BSZ) sc[t] += v;
        __syncthreads();
    }
    if (t < BSZ) {
        int p = e0 + sc[t] - cnt[t];
        cur[t] = p;
        int nd = (b << BSH) + t;
        if (nd < NN) { row_ptr[nd] = p; deg[nd] = cnt[t]; }
    }
    __syncthreads();
    for (int e = e0 + t; e < e1; e += blockDim.x) {
        unsigned int r = tmp[e];
        int ld = r >> 25;
        int k = atomicAdd(&cur[ld], 1);
        cw[k] = r & 0x1FFFFu;
    }
}

// OR deg[src] bits into cw entries
__global__ void packdeg_kernel(unsigned int* __restrict__ cw, const int* __restrict__ deg) {
    int e = blockIdx.x * blockDim.x + threadIdx.x;
    if (e >= NE) return;
    unsigned int q = cw[e];
    int dg = deg[q];
    if (dg > 32767) dg = 32767;
    cw[e] = q | ((unsigned int)dg << 17);
}

// ---------------- fp16 converts for MFMA ----------------

__global__ void cvtx_kernel(const float4* __restrict__ X, half4* __restrict__ Xh, int tot4) {
    int i = blockIdx.x * blockDim.x + threadIdx.x;
    if (i >= tot4) return;
    float4 v = X[i];
    half4 h;
    h.x = (half1)v.x; h.y = (half1)v.y; h.z = (half1)v.z; h.w = (half1)v.w;
    Xh[i] = h;
}

// Wt[og][kd] = W1[og>>6][kd][og&63], fp16 ; Wt is [512][128]
__global__ void transw_kernel(const float* __restrict__ W, half1* __restrict__ Wt) {
    int i = blockIdx.x * blockDim.x + threadIdx.x;
    if (i >= 512 * 128) return;
    int kd = i >> 9;
    int og = i & 511;
    int k = og >> 6, o = og & 63;
    Wt[(size_t)og * 128 + kd] = (half1)W[((size_t)k * 128 + kd) * 64 + o];
}

// ---------------- W padding ----------------
__global__ void padw_kernel(const float* __restrict__ src, float* __restrict__ dst,
                            int K, int dins, int douts, int dind, int doutd) {
    int i = blockIdx.x * blockDim.x + threadIdx.x;
    int tot = K * dind * doutd;
    if (i >= tot) return;
    int o = i % doutd;
    int r = i / doutd;
    int dd = r % dind;
    int k = r / dind;
    dst[i] = (dd < dins && o < douts) ? src[((size_t)k * dins + dd) * douts + o] : 0.f;
}

// ---------------- Clenshaw prop, h8 (16B) gathers — dim == 64 ----------------
__global__ void proph8_kernel(const h8* __restrict__ feat, const h8* __restrict__ sub,
                              const h8* __restrict__ add, h8* __restrict__ outh,
                              f8* __restrict__ outf,
                              const int* __restrict__ row_ptr, const unsigned int* __restrict__ cw,
                              int n, float scale, int has_sub, int bnrelu,
                              const float* __restrict__ bn_g, const float* __restrict__ bn_b,
                              const float* __restrict__ bn_m, const float* __restrict__ bn_v) {
    int idx = blockIdx.x * blockDim.x + threadIdx.x;
    if (idx >= n * 8) return;
    int nd = idx >> 3;
    int f = idx & 7;
    int e0 = row_ptr[nd], e1 = row_ptr[nd + 1];
    f8 a0 = {0.f, 0.f, 0.f, 0.f, 0.f, 0.f, 0.f, 0.f}, a1 = a0, a2 = a0, a3 = a0;
    int e = e0;
    for (; e + 8 <= e1; e += 8) {
        unsigned int q0 = cw[e], q1 = cw[e + 1], q2 = cw[e + 2], q3 = cw[e + 3];
        unsigned int q4 = cw[e + 4], q5 = cw[e + 5], q6 = cw[e + 6], q7 = cw[e + 7];
        f8 v0 = __builtin_convertvector(feat[(size_t)(q0 & 0x1FFFFu) * 8 + f], f8);
        f8 v1 = __builtin_convertvector(feat[(size_t)(q1 & 0x1FFFFu) * 8 + f], f8);
        f8 v2 = __builtin_convertvector(feat[(size_t)(q2 & 0x1FFFFu) * 8 + f], f8);
        f8 v3 = __builtin_convertvector(feat[(size_t)(q3 & 0x1FFFFu) * 8 + f], f8);
        f8 v4 = __builtin_convertvector(feat[(size_t)(q4 & 0x1FFFFu) * 8 + f], f8);
        f8 v5 = __builtin_convertvector(feat[(size_t)(q5 & 0x1FFFFu) * 8 + f], f8);
        f8 v6 = __builtin_convertvector(feat[(size_t)(q6 & 0x1FFFFu) * 8 + f], f8);
        f8 v7 = __builtin_convertvector(feat[(size_t)(q7 & 0x1FFFFu) * 8 + f], f8);
        a0 += wsrc(q0) * v0;
        a1 += wsrc(q1) * v1;
        a2 += wsrc(q2) * v2;
        a3 += wsrc(q3) * v3;
        a0 += wsrc(q4) * v4;
        a1 += wsrc(q5) * v5;
        a2 += wsrc(q6) * v6;
        a3 += wsrc(q7) * v7;
    }
    for (; e + 4 <= e1; e += 4) {
        unsigned int q0 = cw[e], q1 = cw[e + 1], q2 = cw[e + 2], q3 = cw[e + 3];
        f8 v0 = __builtin_convertvector(feat[(size_t)(q0 & 0x1FFFFu) * 8 + f], f8);
        f8 v1 = __builtin_convertvector(feat[(size_t)(q1 & 0x1FFFFu) * 8 + f], f8);
        f8 v2 = __builtin_convertvector(feat[(size_t)(q2 & 0x1FFFFu) * 8 + f], f8);
        f8 v3 = __builtin_convertvector(feat[(size_t)(q3 & 0x1FFFFu) * 8 + f], f8);
        a0 += wsrc(q0) * v0;
        a1 += wsrc(q1) * v1;
        a2 += wsrc(q2) * v2;
        a3 += wsrc(q3) * v3;
    }
    for (; e < e1; ++e) {
        unsigned int q = cw[e];
        a0 += wsrc(q) * __builtin_convertvector(feat[(size_t)(q & 0x1FFFFu) * 8 + f], f8);
    }
    int degd = e1 - e0;
    float ms = (degd > 0) ? -scale * rsqrtf((float)degd) : 0.f;
    f8 r = ((a0 + a1) + (a2 + a3)) * ms;
    if (has_sub) r -= __builtin_convertvector(sub[idx], f8);
    r += __builtin_convertvector(__builtin_nontemporal_load(&add[idx]), f8);
    if (bnrelu) {
#pragma unroll
        for (int c = 0; c < 8; ++c) {
            int o = f * 8 + c;
            float sc = bn_g[o] * rsqrtf(bn_v[o] + BN_EPS);
            r[c] = fmaxf(fmaf(r[c] - bn_m[o], sc, bn_b[o]), 0.f);
        }
    }
    if (outf) {
        outf[idx] = r;
    } else {
        outh[idx] = __builtin_convertvector(r, h8);
    }
}

// ---------------- Clenshaw prop, half4 gathers — small dims ----------------
__global__ void proph_kernel(const half4* __restrict__ feat, const half4* __restrict__ sub,
                             const half4* __restrict__ add, half4* __restrict__ outh,
                             f4* __restrict__ outf,
                             const int* __restrict__ row_ptr, const unsigned int* __restrict__ cw,
                             int n, int dim4, float scale, int has_sub,
                             int bnrelu, int used,
                             const float* __restrict__ bn_g, const float* __restrict__ bn_b,
                             const float* __restrict__ bn_m, const float* __restrict__ bn_v) {
    int idx = blockIdx.x * blockDim.x + threadIdx.x;
    if (idx >= n * dim4) return;
    int nd = idx / dim4;
    int f = idx - nd * dim4;
    int e0 = row_ptr[nd], e1 = row_ptr[nd + 1];
    f4 a0 = {0.f, 0.f, 0.f, 0.f}, a1 = a0, a2 = a0, a3 = a0;
    int e = e0;
    for (; e + 4 <= e1; e += 4) {
        unsigned int q0 = cw[e], q1 = cw[e + 1], q2 = cw[e + 2], q3 = cw[e + 3];
        f4 v0 = __builtin_convertvector(feat[(size_t)(q0 & 0x1FFFFu) * dim4 + f], f4);
        f4 v1 = __builtin_convertvector(feat[(size_t)(q1 & 0x1FFFFu) * dim4 + f], f4);
        f4 v2 = __builtin_convertvector(feat[(size_t)(q2 & 0x1FFFFu) * dim4 + f], f4);
        f4 v3 = __builtin_convertvector(feat[(size_t)(q3 & 0x1FFFFu) * dim4 + f], f4);
        a0 += wsrc(q0) * v0;
        a1 += wsrc(q1) * v1;
        a2 += wsrc(q2) * v2;
        a3 += wsrc(q3) * v3;
    }
    for (; e < e1; ++e) {
        unsigned int q = cw[e];
        a0 += wsrc(q) * __builtin_convertvector(feat[(size_t)(q & 0x1FFFFu) * dim4 + f], f4);
    }
    int degd = e1 - e0;
    float ms = (degd > 0) ? -scale * rsqrtf((float)degd) : 0.f;
    f4 r = ((a0 + a1) + (a2 + a3)) * ms;
    if (has_sub) r -= __builtin_convertvector(sub[idx], f4);
    r += __builtin_convertvector(__builtin_nontemporal_load(&add[idx]), f4);
    if (bnrelu) {
#pragma unroll
        for (int c = 0; c < 4; ++c) {
            int o = f * 4 + c;
            if (o < used) {
                float sc = bn_g[o] * rsqrtf(bn_v[o] + BN_EPS);
                r[c] = fmaxf(fmaf(r[c] - bn_m[o], sc, bn_b[o]), 0.f);
            } else r[c] = 0.f;
        }
    }
    if (outf) {
        outf[idx] = r;
    } else {
        half4 h;
        h.x = (half1)r.x; h.y = (half1)r.y; h.z = (half1)r.z; h.w = (half1)r.w;
        outh[idx] = h;
    }
}

// layer-4 final: fp16 gathers/streams at stride 12 (dim4=3), fp32 out at stride 10
__global__ void propl_kernel(const half4* __restrict__ feat, const half4* __restrict__ sub,
                             const half4* __restrict__ add, float* __restrict__ out,
                             const int* __restrict__ row_ptr, const unsigned int* __restrict__ cw,
                             int n) {
    int idx = blockIdx.x * blockDim.x + threadIdx.x;
    if (idx >= n * 3) return;
    int nd = idx / 3;
    int f = idx - nd * 3;
    int e0 = row_ptr[nd], e1 = row_ptr[nd + 1];
    f4 a0 = {0.f, 0.f, 0.f, 0.f}, a1 = a0, a2 = a0, a3 = a0;
    int e = e0;
    for (; e + 4 <= e1; e += 4) {
        unsigned int q0 = cw[e], q1 = cw[e + 1], q2 = cw[e + 2], q3 = cw[e + 3];
        a0 += wsrc(q0) * __builtin_convertvector(feat[(size_t)(q0 & 0x1FFFFu) * 3 + f], f4);
        a1 += wsrc(q1) * __builtin_convertvector(feat[(size_t)(q1 & 0x1FFFFu) * 3 + f], f4);
        a2 += wsrc(q2) * __builtin_convertvector(feat[(size_t)(q2 & 0x1FFFFu) * 3 + f], f4);
        a3 += wsrc(q3) * __builtin_convertvector(feat[(size_t)(q3 & 0x1FFFFu) * 3 + f], f4);
    }
    for (; e < e1; ++e) {
        unsigned int q = cw[e];
        a0 += wsrc(q) * __builtin_convertvector(feat[(size_t)(q & 0x1FFFFu) * 3 + f], f4);
    }
    int degd = e1 - e0;
    float ms = (degd > 0) ? -rsqrtf((float)degd) : 0.f;
    f4 r = ((a0 + a1) + (a2 + a3)) * ms;
    r -= __builtin_convertvector(sub[idx], f4);
    r += __builtin_convertvector(add[idx], f4);
    int o = f * 4;
    float* orow = out + (size_t)nd * 10;
    if (o + 0 < 10) orow[o + 0] = r.x;
    if (o + 1 < 10) orow[o + 1] = r.y;
    if (o + 2 < 10) orow[o + 2] = r.z;
    if (o + 3 < 10) orow[o + 3] = r.w;
}

// ---------------- layer-1 GEMM via MFMA (8 waves = 8 k-slices; LDS-staged epilogue) ----
#define LSTR 72  // LDS row stride in halves (64 data + 8 pad -> 2-way bank aliasing, free)
__global__ __launch_bounds__(512) void gemm_mfma_kernel(
        const half1* __restrict__ Xh, const half1* __restrict__ Wt,
        const float* __restrict__ bias, half1* __restrict__ CB, int n) {
    __shared__ half1 lds[8 * 64 * LSTR];
    int lane = threadIdx.x & 63;
    int ks = threadIdx.x >> 6;   // 0..7
    int m16 = lane & 15;
    int quad = lane >> 4;
    int ntile = blockIdx.x * 64;

    f4 acc[4][4];
#pragma unroll
    for (int nt = 0; nt < 4; ++nt)
#pragma unroll
        for (int i = 0; i < 4; ++i) acc[nt][i] = (f4){0.f, 0.f, 0.f, 0.f};

#pragma unroll
    for (int kc = 0; kc < 4; ++kc) {
        int koff = kc * 32 + quad * 8;
        h8 a[4];
#pragma unroll
        for (int i = 0; i < 4; ++i)
            a[i] = *(const h8*)(Wt + (size_t)(ks * 64 + i * 16 + m16) * 128 + koff);
        h8 b[4];
#pragma unroll
        for (int nt = 0; nt < 4; ++nt) {
            int node = min(ntile + nt * 16 + m16, n - 1);
            b[nt] = *(const h8*)(Xh + (size_t)node * 128 + koff);
        }
#pragma unroll
        for (int nt = 0; nt < 4; ++nt)
#pragma unroll
            for (int i = 0; i < 4; ++i)
                acc[nt][i] = __builtin_amdgcn_mfma_f32_16x16x32_f16(a[i], b[nt], acc[nt][i], 0, 0, 0);
    }

    // stage to LDS: [ks][node_l (64)][out (64, stride LSTR)]
#pragma unroll
    for (int nt = 0; nt < 4; ++nt) {
        int node_l = nt * 16 + m16;
#pragma unroll
        for (int i = 0; i < 4; ++i) {
            int ob = i * 16 + quad * 4;
            f4 v = acc[nt][i];
            if (ks == 0) {
                const f4 b4 = *(const f4*)(bias + ob);
                v += b4;
            }
            half4 h;
            h.x = (half1)v[0]; h.y = (half1)v[1]; h.z = (half1)v[2]; h.w = (half1)v[3];
            *(half4*)(lds + ((size_t)ks * 64 + node_l) * LSTR + ob) = h;
        }
    }
    __syncthreads();

    // coalesced write-out: wave ks copies its 64x128B slab; 8 lanes per node row
    int nl0 = lane >> 3;    // 0..7
    int chunk = lane & 7;   // 0..7, 16B each
#pragma unroll
    for (int j = 0; j < 8; ++j) {
        int node_l = j * 8 + nl0;
        int node = ntile + node_l;
        if (node < n) {
            h8 v = *(const h8*)(lds + ((size_t)ks * 64 + node_l) * LSTR + chunk * 8);
            *(h8*)(CB + ((size_t)ks * n + node) * 64 + chunk * 8) = v;
        }
    }
}

// ---------------- small-layer GEMM: block = KK waves, wave k, lane = node -------------
template <int KK, int DIN4, int NACC>
__global__ void gemm_smallw_kernel(const float* __restrict__ X, const float* __restrict__ Wp,
                                   const float* __restrict__ bias, int dout,
                                   half4* __restrict__ CB, int n) {
    int lane = threadIdx.x & 63;
    int k = __builtin_amdgcn_readfirstlane((int)(threadIdx.x >> 6));
    int node0 = blockIdx.x * 64 + lane;
    int node = min(node0, n - 1);
    f4 acc[NACC];
#pragma unroll
    for (int i = 0; i < NACC; ++i) {
        f4 v = {0.f, 0.f, 0.f, 0.f};
        if (k == 0 && bias) {
#pragma unroll
            for (int c = 0; c < 4; ++c) {
                int o = i * 4 + c;
                v[c] = (o < dout) ? bias[o] : 0.f;
            }
        }
        acc[i] = v;
    }
    const f4* Xr = (const f4*)(X + (size_t)node * (DIN4 * 4));
    const f4* Wk = (const f4*)(Wp + (size_t)k * (DIN4 * 4) * (NACC * 4));
    for (int d4 = 0; d4 < DIN4; ++d4) {
        f4 xv = Xr[d4];
#pragma unroll
        for (int j = 0; j < 4; ++j) {
            float xs = xv[j];
#pragma unroll
            for (int i = 0; i < NACC; ++i)
                acc[i] += xs * Wk[(d4 * 4 + j) * NACC + i];
        }
    }
    if (node0 < n) {
        size_t base = ((size_t)k * n + node) * NACC;
#pragma unroll
        for (int i = 0; i < NACC; ++i) {
            half4 h;
            h.x = (half1)acc[i].x; h.y = (half1)acc[i].y;
            h.z = (half1)acc[i].z; h.w = (half1)acc[i].w;
            CB[base + i] = h;
        }
    }
}

// ---------------- host driver ----------------

extern "C" void kernel_launch(void* const* d_in, const int* in_sizes, int n_in,
                              void* d_out, int out_size, void* d_ws, size_t ws_size,
                              hipStream_t stream) {
    const float* x  = (const float*)d_in[0];
    const int*   ei = (const int*)d_in[1];
    const float* Wl[4] = {(const float*)d_in[2], (const float*)d_in[4],
                          (const float*)d_in[6], (const float*)d_in[8]};
    const float* bl[4] = {(const float*)d_in[3], (const float*)d_in[5],
                          (const float*)d_in[7], (const float*)d_in[9]};
    const float* bn[3][4];
    for (int l = 0; l < 3; ++l)
        for (int j = 0; j < 4; ++j)
            bn[l][j] = (const float*)d_in[10 + 4 * l + j];

    char* ws = (char*)d_ws;
    size_t off = 0;
    auto alloc = [&](size_t bytes) -> void* {
        void* p = (void*)(ws + off);
        off = (off + bytes + 255) & ~(size_t)255;
        return p;
    };
    int*   deg      = (int*)alloc(NN * 4);
    int*   row_ptr  = (int*)alloc((NN + 1) * 4);
    int*   bstart   = (int*)alloc((NBUCK + 1) * 4);
    unsigned int* cw = (unsigned int*)alloc((size_t)NE * 4);
    half1* CB1h    = (half1*)alloc((size_t)8 * NN * 64 * 2);
    half1* CBsh    = (half1*)alloc((size_t)6 * NN * 20 * 2);
    half1* S0      = (half1*)alloc((size_t)NN * 64 * 2);
    half1* S1      = (half1*)alloc((size_t)NN * 64 * 2);
    half1* S2      = (half1*)alloc((size_t)NN * 64 * 2);
    float* H1f     = (float*)alloc((size_t)NN * 64 * 4);
    float* H2f     = (float*)alloc((size_t)NN * 20 * 4);
    float* H3f     = (float*)alloc((size_t)NN * 12 * 4);
    float* Wp2     = (float*)alloc((size_t)6 * 64 * 20 * 4);
    float* Wp3     = (float*)alloc((size_t)4 * 20 * 12 * 4);
    float* Wp4     = (float*)alloc((size_t)4 * 12 * 12 * 4);
    half1* Xh      = (half1*)alloc((size_t)NN * 128 * 2);
    half1* Wt1     = (half1*)alloc((size_t)512 * 128 * 2);

    // CSR-build scratch aliased into CB1h (consumed before gemm_mfma writes it):
    unsigned int* tmp = (unsigned int*)CB1h;                // 6.4 MB
    int* hist_g = (int*)((char*)CB1h + (16u << 20));        // NC*NBUCK*4 = 600 KB
    int* off_g  = hist_g + NC * NBUCK;                      // 600 KB

    const int* srcp = ei;
    const int* dstp = ei + NE;
    const int NB = divup(NN, 64);

    histb_kernel<<<NC, 256, 0, stream>>>(dstp, hist_g);
    bscan1_kernel<<<1, 1024, 0, stream>>>(hist_g, bstart, row_ptr);
    boff_kernel<<<divup(NBUCK, 256), 256, 0, stream>>>(bstart, hist_g, off_g);
    binscatter_kernel<<<NC * 8, 256, 0, stream>>>(srcp, dstp, off_g, tmp);
    finalize_kernel<<<NBUCK, 256, 0, stream>>>(tmp, bstart, row_ptr, deg, cw);
    packdeg_kernel<<<divup(NE, 256), 256, 0, stream>>>(cw, deg);

    cvtx_kernel<<<divup(NN * 32, 256), 256, 0, stream>>>((const float4*)x, (half4*)Xh, NN * 32);
    transw_kernel<<<divup(512 * 128, 256), 256, 0, stream>>>(Wl[0], Wt1);
    padw_kernel<<<divup(6 * 64 * 20, 256), 256, 0, stream>>>(Wl[1], Wp2, 6, 64, 18, 64, 20);
    padw_kernel<<<divup(4 * 20 * 12, 256), 256, 0, stream>>>(Wl[2], Wp3, 4, 18, 9, 20, 12);
    padw_kernel<<<divup(4 * 12 * 12, 256), 256, 0, stream>>>(Wl[3], Wp4, 4, 9, 10, 12, 12);

    // dim-64 prop (h8 gathers)
    auto prop1 = [&](const half1* feat, const half1* sub, const half1* add,
                     half1* outh, float* outf, float scale, int bnrelu,
                     const float* g, const float* bb, const float* m, const float* v) {
        proph8_kernel<<<divup(NN * 8, 256), 256, 0, stream>>>(
            (const h8*)feat, (const h8*)sub, (const h8*)add,
            (h8*)outh, (f8*)outf, row_ptr, cw, NN, scale,
            sub != nullptr, bnrelu, g, bb, m, v);
    };
    // small-dim prop (half4 gathers)
    auto prop = [&](const half1* feat, const half1* sub, const half1* add,
                    half1* outh, float* outf, int dim4, float scale,
                    int bnrelu, int used, const float* g, const float* bb,
                    const float* m, const float* v) {
        proph_kernel<<<divup(NN * dim4, 256), 256, 0, stream>>>(
            (const half4*)feat, (const half4*)sub, (const half4*)add,
            (half4*)outh, (f4*)outf, row_ptr, cw, NN, dim4, scale,
            sub != nullptr, bnrelu, used, g, bb, m, v);
    };

    // ---- layer 1 (din=128, dout=64, K=8) -> H1f ----
    gemm_mfma_kernel<<<NB, 512, 0, stream>>>(Xh, Wt1, bl[0], CB1h, NN);
    {
        auto C = [&](int k) { return (const half1*)(CB1h + (size_t)k * NN * 64); };
        prop1(C(7), nullptr, C(6), S0, nullptr, 2.f, 0, 0, 0, 0, 0);
        prop1(S0, C(7), C(5), S1, nullptr, 2.f, 0, 0, 0, 0, 0);
        prop1(S1, S0, C(4), S2, nullptr, 2.f, 0, 0, 0, 0, 0);
        prop1(S2, S1, C(3), S0, nullptr, 2.f, 0, 0, 0, 0, 0);
        prop1(S0, S2, C(2), S1, nullptr, 2.f, 0, 0, 0, 0, 0);
        prop1(S1, S0, C(1), S2, nullptr, 2.f, 0, 0, 0, 0, 0);
        prop1(S2, S1, C(0), nullptr, H1f, 1.f, 1,
              bn[0][0], bn[0][1], bn[0][2], bn[0][3]);
    }

    // ---- layer 2 (din=64, dout=18 pad 20, K=6): X=H1f -> H2f ----
    gemm_smallw_kernel<6, 16, 5><<<NB, 384, 0, stream>>>(H1f, Wp2, bl[1], 18,
                                                         (half4*)CBsh, NN);
    {
        auto C = [&](int k) { return (const half1*)(CBsh + (size_t)k * NN * 20); };
        prop(C(5), nullptr, C(4), S0, nullptr, 5, 2.f, 0, 18, 0, 0, 0, 0);
        prop(S0, C(5), C(3), S1, nullptr, 5, 2.f, 0, 18, 0, 0, 0, 0);
        prop(S1, S0, C(2), S2, nullptr, 5, 2.f, 0, 18, 0, 0, 0, 0);
        prop(S2, S1, C(1), S0, nullptr, 5, 2.f, 0, 18, 0, 0, 0, 0);
        prop(S0, S2, C(0), nullptr, H2f, 5, 1.f, 1, 18,
             bn[1][0], bn[1][1], bn[1][2], bn[1][3]);
    }

    // ---- layer 3 (din=18 str20, dout=9 pad 12, K=4): X=H2f -> H3f ----
    gemm_smallw_kernel<4, 5, 3><<<NB, 256, 0, stream>>>(H2f, Wp3, bl[2], 9,
                                                        (half4*)CBsh, NN);
    {
        auto C = [&](int k) { return (const half1*)(CBsh + (size_t)k * NN * 12); };
        prop(C(3), nullptr, C(2), S0, nullptr, 3, 2.f, 0, 9, 0, 0, 0, 0);
        prop(S0, C(3), C(1), S1, nullptr, 3, 2.f, 0, 9, 0, 0, 0, 0);
        prop(S1, S0, C(0), nullptr, H3f, 3, 1.f, 1, 9,
             bn[2][0], bn[2][1], bn[2][2], bn[2][3]);
    }

    // ---- layer 4 (din=9 str12, dout=10 pad 12, K=4): X=H3f -> d_out ----
    gemm_smallw_kernel<4, 3, 3><<<NB, 256, 0, stream>>>(H3f, Wp4, bl[3], 10,
                                                        (half4*)CBsh, NN);
    {
        auto C = [&](int k) { return (const half1*)(CBsh + (size_t)k * NN * 12); };
        prop(C(3), nullptr, C(2), S0, nullptr, 3, 2.f, 0, 10, 0, 0, 0, 0);
        prop(S0, C(3), C(1), S1, nullptr, 3, 2.f, 0, 10, 0, 0, 0, 0);
        propl_kernel<<<divup(NN * 3, 256), 256, 0, stream>>>(
            (const half4*)S1, (const half4*)S0, (const half4*)CBsh,
            (float*)d_out, row_ptr, cw, NN);
    }
}

// Round 5
// 795.121 us; speedup vs baseline: 1.1110x; 1.0007x over previous
//
#include <hip/hip_runtime.h>

#define NN 100000
#define NE 1600000
#define BN_EPS 1e-5f

// CSR binning parameters
#define BSH 7
#define BSZ (1 << BSH)   // 128 dsts per bucket
#define NBUCK 782        // divup(NN, BSZ)
#define NC 192           // edge chunks
#define CE 8334          // divup(NE, NC)

typedef _Float16 half1;
typedef _Float16 half4 __attribute__((ext_vector_type(4)));
typedef _Float16 h8 __attribute__((ext_vector_type(8)));
typedef float f4 __attribute__((ext_vector_type(4)));
typedef float f8 __attribute__((ext_vector_type(8)));

static inline int divup(int a, int b) { return (a + b - 1) / b; }

// per-edge source weight from packed entry: src in [0:17), deg_src in [17:32)
__device__ __forceinline__ float wsrc(unsigned int q) {
    unsigned int dg = q >> 17;
    return dg ? rsqrtf((float)dg) : 0.f;
}

// ---------------- preprocessing (no global atomics) ----------------

// per-chunk bucket histogram, LDS only
__global__ void histb_kernel(const int* __restrict__ dst, int* __restrict__ hist_g) {
    __shared__ int h[NBUCK];
    int c = blockIdx.x;
    for (int i = threadIdx.x; i < NBUCK; i += blockDim.x) h[i] = 0;
    __syncthreads();
    int e0 = c * CE, e1 = min(e0 + CE, NE);
    for (int e = e0 + threadIdx.x; e < e1; e += blockDim.x)
        atomicAdd(&h[dst[e] >> BSH], 1);
    __syncthreads();
    for (int i = threadIdx.x; i < NBUCK; i += blockDim.x) hist_g[c * NBUCK + i] = h[i];
}

// single block: bucket totals + exclusive scan -> bucket_start[0..NBUCK]
__global__ void bscan1_kernel(const int* __restrict__ hist_g, int* __restrict__ bucket_start,
                              int* __restrict__ row_ptr) {
    __shared__ int sh[1024];
    int t = threadIdx.x;
    int tot = 0;
    if (t < NBUCK)
        for (int c = 0; c < NC; ++c) tot += hist_g[c * NBUCK + t];
    sh[t] = (t < NBUCK) ? tot : 0;
    __syncthreads();
    for (int off = 1; off < 1024; off <<= 1) {
        int v = (t >= off) ? sh[t - off] : 0;
        __syncthreads();
        sh[t] += v;
        __syncthreads();
    }
    if (t < NBUCK) bucket_start[t] = sh[t] - tot;
    if (t == 0) { bucket_start[NBUCK] = NE; row_ptr[NN] = NE; }
}

// off_g[c][b] = bucket_start[b] + prefix over chunks
__global__ void boff_kernel(const int* __restrict__ bucket_start, const int* __restrict__ hist_g,
                            int* __restrict__ off_g) {
    int b = blockIdx.x * blockDim.x + threadIdx.x;
    if (b >= NBUCK) return;
    int run = bucket_start[b];
#pragma unroll 4
    for (int c = 0; c < NC; ++c) {
        off_g[c * NBUCK + b] = run;
        run += hist_g[c * NBUCK + b];
    }
}

// XCD-pinned bucket scatter: 4B packed tmp entries (src | local_d<<25)
__global__ void binscatter_kernel(const int* __restrict__ src, const int* __restrict__ dst,
                                  const int* __restrict__ off_g, unsigned int* __restrict__ tmp) {
    __shared__ int off_l[NBUCK];
    int myx = blockIdx.x & 7;
    int c = blockIdx.x >> 3;
    for (int i = threadIdx.x; i < NBUCK; i += blockDim.x)
        off_l[i] = ((i & 7) == myx) ? off_g[c * NBUCK + i] : 0;
    __syncthreads();
    int e0 = c * CE, e1 = min(e0 + CE, NE);
    for (int e = e0 + threadIdx.x; e < e1; e += blockDim.x) {
        int d = dst[e];
        int b = d >> BSH;
        if ((b & 7) != myx) continue;
        int s = src[e];
        int pos = atomicAdd(&off_l[b], 1);
        tmp[pos] = (unsigned int)s | ((unsigned int)(d & (BSZ - 1)) << 25);
    }
}

// per-bucket: LDS degree count + scan -> deg, row_ptr, CSR placement (src-only cw)
__global__ void finalize_kernel(const unsigned int* __restrict__ tmp,
                                const int* __restrict__ bucket_start,
                                int* __restrict__ row_ptr, int* __restrict__ deg,
                                unsigned int* __restrict__ cw) {
    __shared__ int cnt[BSZ], sc[BSZ], cur[BSZ];
    int b = blockIdx.x, t = threadIdx.x;
    int e0 = bucket_start[b], e1 = bucket_start[b + 1];
    if (t < BSZ) cnt[t] = 0;
    __syncthreads();
    for (int e = e0 + t; e < e1; e += blockDim.x) atomicAdd(&cnt[tmp[e] >> 25], 1);
    __syncthreads();
    if (t < BSZ) sc[t] = cnt[t];
    __syncthreads();
    for (int off = 1; off < BSZ; off <<= 1) {
        int v = (t >= off && t < BSZ) ? sc[t - off] : 0;
        __syncthreads();
        if (t < BSZ) sc[t] += v;
        __syncthreads();
    }
    if (t < BSZ) {
        int p = e0 + sc[t] - cnt[t];
        cur[t] = p;
        int nd = (b << BSH) + t;
        if (nd < NN) { row_ptr[nd] = p; deg[nd] = cnt[t]; }
    }
    __syncthreads();
    for (int e = e0 + t; e < e1; e += blockDim.x) {
        unsigned int r = tmp[e];
        int ld = r >> 25;
        int k = atomicAdd(&cur[ld], 1);
        cw[k] = r & 0x1FFFFu;
    }
}

// OR deg[src] bits into cw entries
__global__ void packdeg_kernel(unsigned int* __restrict__ cw, const int* __restrict__ deg) {
    int e = blockIdx.x * blockDim.x + threadIdx.x;
    if (e >= NE) return;
    unsigned int q = cw[e];
    int dg = deg[q];
    if (dg > 32767) dg = 32767;
    cw[e] = q | ((unsigned int)dg << 17);
}

// ---------------- fp16 converts for MFMA ----------------

__global__ void cvtx_kernel(const float4* __restrict__ X, half4* __restrict__ Xh, int tot4) {
    int i = blockIdx.x * blockDim.x + threadIdx.x;
    if (i >= tot4) return;
    float4 v = X[i];
    half4 h;
    h.x = (half1)v.x; h.y = (half1)v.y; h.z = (half1)v.z; h.w = (half1)v.w;
    Xh[i] = h;
}

// Wt[og][kd] = W1[og>>6][kd][og&63], fp16 ; Wt is [512][128]
__global__ void transw_kernel(const float* __restrict__ W, half1* __restrict__ Wt) {
    int i = blockIdx.x * blockDim.x + threadIdx.x;
    if (i >= 512 * 128) return;
    int kd = i >> 9;
    int og = i & 511;
    int k = og >> 6, o = og & 63;
    Wt[(size_t)og * 128 + kd] = (half1)W[((size_t)k * 128 + kd) * 64 + o];
}

// ---------------- W padding ----------------
__global__ void padw_kernel(const float* __restrict__ src, float* __restrict__ dst,
                            int K, int dins, int douts, int dind, int doutd) {
    int i = blockIdx.x * blockDim.x + threadIdx.x;
    int tot = K * dind * doutd;
    if (i >= tot) return;
    int o = i % doutd;
    int r = i / doutd;
    int dd = r % dind;
    int k = r / dind;
    dst[i] = (dd < dins && o < douts) ? src[((size_t)k * dins + dd) * douts + o] : 0.f;
}

// ---------------- Clenshaw prop, h8 (16B) gathers — dim == 64 ----------------
__global__ void proph8_kernel(const h8* __restrict__ feat, const h8* __restrict__ sub,
                              const h8* __restrict__ add, h8* __restrict__ outh,
                              f8* __restrict__ outf,
                              const int* __restrict__ row_ptr, const unsigned int* __restrict__ cw,
                              int n, float scale, int has_sub, int bnrelu,
                              const float* __restrict__ bn_g, const float* __restrict__ bn_b,
                              const float* __restrict__ bn_m, const float* __restrict__ bn_v) {
    int idx = blockIdx.x * blockDim.x + threadIdx.x;
    if (idx >= n * 8) return;
    int nd = idx >> 3;
    int f = idx & 7;
    int e0 = row_ptr[nd], e1 = row_ptr[nd + 1];
    f8 a0 = {0.f, 0.f, 0.f, 0.f, 0.f, 0.f, 0.f, 0.f}, a1 = a0, a2 = a0, a3 = a0;
    int e = e0;
    for (; e + 8 <= e1; e += 8) {
        unsigned int q0 = cw[e], q1 = cw[e + 1], q2 = cw[e + 2], q3 = cw[e + 3];
        unsigned int q4 = cw[e + 4], q5 = cw[e + 5], q6 = cw[e + 6], q7 = cw[e + 7];
        f8 v0 = __builtin_convertvector(feat[(size_t)(q0 & 0x1FFFFu) * 8 + f], f8);
        f8 v1 = __builtin_convertvector(feat[(size_t)(q1 & 0x1FFFFu) * 8 + f], f8);
        f8 v2 = __builtin_convertvector(feat[(size_t)(q2 & 0x1FFFFu) * 8 + f], f8);
        f8 v3 = __builtin_convertvector(feat[(size_t)(q3 & 0x1FFFFu) * 8 + f], f8);
        f8 v4 = __builtin_convertvector(feat[(size_t)(q4 & 0x1FFFFu) * 8 + f], f8);
        f8 v5 = __builtin_convertvector(feat[(size_t)(q5 & 0x1FFFFu) * 8 + f], f8);
        f8 v6 = __builtin_convertvector(feat[(size_t)(q6 & 0x1FFFFu) * 8 + f], f8);
        f8 v7 = __builtin_convertvector(feat[(size_t)(q7 & 0x1FFFFu) * 8 + f], f8);
        a0 += wsrc(q0) * v0;
        a1 += wsrc(q1) * v1;
        a2 += wsrc(q2) * v2;
        a3 += wsrc(q3) * v3;
        a0 += wsrc(q4) * v4;
        a1 += wsrc(q5) * v5;
        a2 += wsrc(q6) * v6;
        a3 += wsrc(q7) * v7;
    }
    for (; e + 4 <= e1; e += 4) {
        unsigned int q0 = cw[e], q1 = cw[e + 1], q2 = cw[e + 2], q3 = cw[e + 3];
        f8 v0 = __builtin_convertvector(feat[(size_t)(q0 & 0x1FFFFu) * 8 + f], f8);
        f8 v1 = __builtin_convertvector(feat[(size_t)(q1 & 0x1FFFFu) * 8 + f], f8);
        f8 v2 = __builtin_convertvector(feat[(size_t)(q2 & 0x1FFFFu) * 8 + f], f8);
        f8 v3 = __builtin_convertvector(feat[(size_t)(q3 & 0x1FFFFu) * 8 + f], f8);
        a0 += wsrc(q0) * v0;
        a1 += wsrc(q1) * v1;
        a2 += wsrc(q2) * v2;
        a3 += wsrc(q3) * v3;
    }
    for (; e < e1; ++e) {
        unsigned int q = cw[e];
        a0 += wsrc(q) * __builtin_convertvector(feat[(size_t)(q & 0x1FFFFu) * 8 + f], f8);
    }
    int degd = e1 - e0;
    float ms = (degd > 0) ? -scale * rsqrtf((float)degd) : 0.f;
    f8 r = ((a0 + a1) + (a2 + a3)) * ms;
    if (has_sub) r -= __builtin_convertvector(sub[idx], f8);
    r += __builtin_convertvector(__builtin_nontemporal_load(&add[idx]), f8);
    if (bnrelu) {
#pragma unroll
        for (int c = 0; c < 8; ++c) {
            int o = f * 8 + c;
            float sc = bn_g[o] * rsqrtf(bn_v[o] + BN_EPS);
            r[c] = fmaxf(fmaf(r[c] - bn_m[o], sc, bn_b[o]), 0.f);
        }
    }
    if (outf) {
        outf[idx] = r;
    } else {
        outh[idx] = __builtin_convertvector(r, h8);
    }
}

// ---------------- Clenshaw prop, half4 gathers — small dims ----------------
__global__ void proph_kernel(const half4* __restrict__ feat, const half4* __restrict__ sub,
                             const half4* __restrict__ add, half4* __restrict__ outh,
                             f4* __restrict__ outf,
                             const int* __restrict__ row_ptr, const unsigned int* __restrict__ cw,
                             int n, int dim4, float scale, int has_sub,
                             int bnrelu, int used,
                             const float* __restrict__ bn_g, const float* __restrict__ bn_b,
                             const float* __restrict__ bn_m, const float* __restrict__ bn_v) {
    int idx = blockIdx.x * blockDim.x + threadIdx.x;
    if (idx >= n * dim4) return;
    int nd = idx / dim4;
    int f = idx - nd * dim4;
    int e0 = row_ptr[nd], e1 = row_ptr[nd + 1];
    f4 a0 = {0.f, 0.f, 0.f, 0.f}, a1 = a0, a2 = a0, a3 = a0;
    int e = e0;
    for (; e + 4 <= e1; e += 4) {
        unsigned int q0 = cw[e], q1 = cw[e + 1], q2 = cw[e + 2], q3 = cw[e + 3];
        f4 v0 = __builtin_convertvector(feat[(size_t)(q0 & 0x1FFFFu) * dim4 + f], f4);
        f4 v1 = __builtin_convertvector(feat[(size_t)(q1 & 0x1FFFFu) * dim4 + f], f4);
        f4 v2 = __builtin_convertvector(feat[(size_t)(q2 & 0x1FFFFu) * dim4 + f], f4);
        f4 v3 = __builtin_convertvector(feat[(size_t)(q3 & 0x1FFFFu) * dim4 + f], f4);
        a0 += wsrc(q0) * v0;
        a1 += wsrc(q1) * v1;
        a2 += wsrc(q2) * v2;
        a3 += wsrc(q3) * v3;
    }
    for (; e < e1; ++e) {
        unsigned int q = cw[e];
        a0 += wsrc(q) * __builtin_convertvector(feat[(size_t)(q & 0x1FFFFu) * dim4 + f], f4);
    }
    int degd = e1 - e0;
    float ms = (degd > 0) ? -scale * rsqrtf((float)degd) : 0.f;
    f4 r = ((a0 + a1) + (a2 + a3)) * ms;
    if (has_sub) r -= __builtin_convertvector(sub[idx], f4);
    r += __builtin_convertvector(__builtin_nontemporal_load(&add[idx]), f4);
    if (bnrelu) {
#pragma unroll
        for (int c = 0; c < 4; ++c) {
            int o = f * 4 + c;
            if (o < used) {
                float sc = bn_g[o] * rsqrtf(bn_v[o] + BN_EPS);
                r[c] = fmaxf(fmaf(r[c] - bn_m[o], sc, bn_b[o]), 0.f);
            } else r[c] = 0.f;
        }
    }
    if (outf) {
        outf[idx] = r;
    } else {
        half4 h;
        h.x = (half1)r.x; h.y = (half1)r.y; h.z = (half1)r.z; h.w = (half1)r.w;
        outh[idx] = h;
    }
}

// layer-4 final: fp16 gathers/streams at stride 12 (dim4=3), fp32 out at stride 10
__global__ void propl_kernel(const half4* __restrict__ feat, const half4* __restrict__ sub,
                             const half4* __restrict__ add, float* __restrict__ out,
                             const int* __restrict__ row_ptr, const unsigned int* __restrict__ cw,
                             int n) {
    int idx = blockIdx.x * blockDim.x + threadIdx.x;
    if (idx >= n * 3) return;
    int nd = idx / 3;
    int f = idx - nd * 3;
    int e0 = row_ptr[nd], e1 = row_ptr[nd + 1];
    f4 a0 = {0.f, 0.f, 0.f, 0.f}, a1 = a0, a2 = a0, a3 = a0;
    int e = e0;
    for (; e + 4 <= e1; e += 4) {
        unsigned int q0 = cw[e], q1 = cw[e + 1], q2 = cw[e + 2], q3 = cw[e + 3];
        a0 += wsrc(q0) * __builtin_convertvector(feat[(size_t)(q0 & 0x1FFFFu) * 3 + f], f4);
        a1 += wsrc(q1) * __builtin_convertvector(feat[(size_t)(q1 & 0x1FFFFu) * 3 + f], f4);
        a2 += wsrc(q2) * __builtin_convertvector(feat[(size_t)(q2 & 0x1FFFFu) * 3 + f], f4);
        a3 += wsrc(q3) * __builtin_convertvector(feat[(size_t)(q3 & 0x1FFFFu) * 3 + f], f4);
    }
    for (; e < e1; ++e) {
        unsigned int q = cw[e];
        a0 += wsrc(q) * __builtin_convertvector(feat[(size_t)(q & 0x1FFFFu) * 3 + f], f4);
    }
    int degd = e1 - e0;
    float ms = (degd > 0) ? -rsqrtf((float)degd) : 0.f;
    f4 r = ((a0 + a1) + (a2 + a3)) * ms;
    r -= __builtin_convertvector(sub[idx], f4);
    r += __builtin_convertvector(add[idx], f4);
    int o = f * 4;
    float* orow = out + (size_t)nd * 10;
    if (o + 0 < 10) orow[o + 0] = r.x;
    if (o + 1 < 10) orow[o + 1] = r.y;
    if (o + 2 < 10) orow[o + 2] = r.z;
    if (o + 3 < 10) orow[o + 3] = r.w;
}

// ---------------- layer-1 GEMM via MFMA (8 waves = 8 k-slices) ----------------
// Epilogue: per-wave 32-node LDS slab, two-phase stage->copy, NO barriers
// (each wave reads only what it wrote; DS ops are in-order within a wave).
// LSTR=68 halves = 34 dwords: write starts cover even banks uniformly (4-slot
// minimum for 512B/wave b64 writes, vs 8-way at LSTR=72).
#define LSTR 68
__global__ __launch_bounds__(512) void gemm_mfma_kernel(
        const half1* __restrict__ Xh, const half1* __restrict__ Wt,
        const float* __restrict__ bias, half1* __restrict__ CB, int n) {
    __shared__ half1 lds[8 * 32 * LSTR];  // 34816 B -> 4 blocks/CU
    int lane = threadIdx.x & 63;
    int ks = threadIdx.x >> 6;   // 0..7
    int m16 = lane & 15;
    int quad = lane >> 4;
    int ntile = blockIdx.x * 64;

    f4 acc[4][4];
#pragma unroll
    for (int nt = 0; nt < 4; ++nt)
#pragma unroll
        for (int i = 0; i < 4; ++i) acc[nt][i] = (f4){0.f, 0.f, 0.f, 0.f};

#pragma unroll
    for (int kc = 0; kc < 4; ++kc) {
        int koff = kc * 32 + quad * 8;
        h8 a[4];
#pragma unroll
        for (int i = 0; i < 4; ++i)
            a[i] = *(const h8*)(Wt + (size_t)(ks * 64 + i * 16 + m16) * 128 + koff);
        h8 b[4];
#pragma unroll
        for (int nt = 0; nt < 4; ++nt) {
            int node = min(ntile + nt * 16 + m16, n - 1);
            b[nt] = *(const h8*)(Xh + (size_t)node * 128 + koff);
        }
#pragma unroll
        for (int nt = 0; nt < 4; ++nt)
#pragma unroll
            for (int i = 0; i < 4; ++i)
                acc[nt][i] = __builtin_amdgcn_mfma_f32_16x16x32_f16(a[i], b[nt], acc[nt][i], 0, 0, 0);
    }

    half1* slab = lds + (size_t)ks * 32 * LSTR;
    int nl0 = lane >> 3;    // 0..7
    int chunk = lane & 7;   // 0..7, 16B each
#pragma unroll
    for (int hh = 0; hh < 2; ++hh) {
        // stage 32 nodes (nt = 2*hh, 2*hh+1) into this wave's slab
#pragma unroll
        for (int p = 0; p < 2; ++p) {
            int nt = hh * 2 + p;
            int node_l = p * 16 + m16;
#pragma unroll
            for (int i = 0; i < 4; ++i) {
                int ob = i * 16 + quad * 4;
                f4 v = acc[nt][i];
                if (ks == 0) {
                    const f4 b4 = *(const f4*)(bias + ob);
                    v += b4;
                }
                half4 h;
                h.x = (half1)v[0]; h.y = (half1)v[1]; h.z = (half1)v[2]; h.w = (half1)v[3];
                *(half4*)(slab + node_l * LSTR + ob) = h;
            }
        }
        asm volatile("s_waitcnt lgkmcnt(0)" ::: "memory");  // cross-lane RAW within wave
        // coalesced copy-out: 8 lanes per 128B node row
#pragma unroll
        for (int j = 0; j < 4; ++j) {
            int node_l = j * 8 + nl0;
            int node = ntile + hh * 32 + node_l;
            if (node < n) {
                h8 v = *(const h8*)(slab + node_l * LSTR + chunk * 8);
                *(h8*)(CB + ((size_t)ks * n + node) * 64 + chunk * 8) = v;
            }
        }
        // DS ops in-order per wave: hh=1 restage cannot pass the reads above.
    }
}

// ---------------- small-layer GEMM: block = KK waves, wave k, lane = node -------------
template <int KK, int DIN4, int NACC>
__global__ void gemm_smallw_kernel(const float* __restrict__ X, const float* __restrict__ Wp,
                                   const float* __restrict__ bias, int dout,
                                   half4* __restrict__ CB, int n) {
    int lane = threadIdx.x & 63;
    int k = __builtin_amdgcn_readfirstlane((int)(threadIdx.x >> 6));
    int node0 = blockIdx.x * 64 + lane;
    int node = min(node0, n - 1);
    f4 acc[NACC];
#pragma unroll
    for (int i = 0; i < NACC; ++i) {
        f4 v = {0.f, 0.f, 0.f, 0.f};
        if (k == 0 && bias) {
#pragma unroll
            for (int c = 0; c < 4; ++c) {
                int o = i * 4 + c;
                v[c] = (o < dout) ? bias[o] : 0.f;
            }
        }
        acc[i] = v;
    }
    const f4* Xr = (const f4*)(X + (size_t)node * (DIN4 * 4));
    const f4* Wk = (const f4*)(Wp + (size_t)k * (DIN4 * 4) * (NACC * 4));
    for (int d4 = 0; d4 < DIN4; ++d4) {
        f4 xv = Xr[d4];
#pragma unroll
        for (int j = 0; j < 4; ++j) {
            float xs = xv[j];
#pragma unroll
            for (int i = 0; i < NACC; ++i)
                acc[i] += xs * Wk[(d4 * 4 + j) * NACC + i];
        }
    }
    if (node0 < n) {
        size_t base = ((size_t)k * n + node) * NACC;
#pragma unroll
        for (int i = 0; i < NACC; ++i) {
            half4 h;
            h.x = (half1)acc[i].x; h.y = (half1)acc[i].y;
            h.z = (half1)acc[i].z; h.w = (half1)acc[i].w;
            CB[base + i] = h;
        }
    }
}

// ---------------- host driver ----------------

extern "C" void kernel_launch(void* const* d_in, const int* in_sizes, int n_in,
                              void* d_out, int out_size, void* d_ws, size_t ws_size,
                              hipStream_t stream) {
    const float* x  = (const float*)d_in[0];
    const int*   ei = (const int*)d_in[1];
    const float* Wl[4] = {(const float*)d_in[2], (const float*)d_in[4],
                          (const float*)d_in[6], (const float*)d_in[8]};
    const float* bl[4] = {(const float*)d_in[3], (const float*)d_in[5],
                          (const float*)d_in[7], (const float*)d_in[9]};
    const float* bn[3][4];
    for (int l = 0; l < 3; ++l)
        for (int j = 0; j < 4; ++j)
            bn[l][j] = (const float*)d_in[10 + 4 * l + j];

    char* ws = (char*)d_ws;
    size_t off = 0;
    auto alloc = [&](size_t bytes) -> void* {
        void* p = (void*)(ws + off);
        off = (off + bytes + 255) & ~(size_t)255;
        return p;
    };
    int*   deg      = (int*)alloc(NN * 4);
    int*   row_ptr  = (int*)alloc((NN + 1) * 4);
    int*   bstart   = (int*)alloc((NBUCK + 1) * 4);
    unsigned int* cw = (unsigned int*)alloc((size_t)NE * 4);
    half1* CB1h    = (half1*)alloc((size_t)8 * NN * 64 * 2);
    half1* CBsh    = (half1*)alloc((size_t)6 * NN * 20 * 2);
    half1* S0      = (half1*)alloc((size_t)NN * 64 * 2);
    half1* S1      = (half1*)alloc((size_t)NN * 64 * 2);
    half1* S2      = (half1*)alloc((size_t)NN * 64 * 2);
    float* H1f     = (float*)alloc((size_t)NN * 64 * 4);
    float* H2f     = (float*)alloc((size_t)NN * 20 * 4);
    float* H3f     = (float*)alloc((size_t)NN * 12 * 4);
    float* Wp2     = (float*)alloc((size_t)6 * 64 * 20 * 4);
    float* Wp3     = (float*)alloc((size_t)4 * 20 * 12 * 4);
    float* Wp4     = (float*)alloc((size_t)4 * 12 * 12 * 4);
    half1* Xh      = (half1*)alloc((size_t)NN * 128 * 2);
    half1* Wt1     = (half1*)alloc((size_t)512 * 128 * 2);

    // CSR-build scratch aliased into CB1h (consumed before gemm_mfma writes it):
    unsigned int* tmp = (unsigned int*)CB1h;                // 6.4 MB
    int* hist_g = (int*)((char*)CB1h + (16u << 20));        // NC*NBUCK*4 = 600 KB
    int* off_g  = hist_g + NC * NBUCK;                      // 600 KB

    const int* srcp = ei;
    const int* dstp = ei + NE;
    const int NB = divup(NN, 64);

    histb_kernel<<<NC, 256, 0, stream>>>(dstp, hist_g);
    bscan1_kernel<<<1, 1024, 0, stream>>>(hist_g, bstart, row_ptr);
    boff_kernel<<<divup(NBUCK, 256), 256, 0, stream>>>(bstart, hist_g, off_g);
    binscatter_kernel<<<NC * 8, 256, 0, stream>>>(srcp, dstp, off_g, tmp);
    finalize_kernel<<<NBUCK, 256, 0, stream>>>(tmp, bstart, row_ptr, deg, cw);
    packdeg_kernel<<<divup(NE, 256), 256, 0, stream>>>(cw, deg);

    cvtx_kernel<<<divup(NN * 32, 256), 256, 0, stream>>>((const float4*)x, (half4*)Xh, NN * 32);
    transw_kernel<<<divup(512 * 128, 256), 256, 0, stream>>>(Wl[0], Wt1);
    padw_kernel<<<divup(6 * 64 * 20, 256), 256, 0, stream>>>(Wl[1], Wp2, 6, 64, 18, 64, 20);
    padw_kernel<<<divup(4 * 20 * 12, 256), 256, 0, stream>>>(Wl[2], Wp3, 4, 18, 9, 20, 12);
    padw_kernel<<<divup(4 * 12 * 12, 256), 256, 0, stream>>>(Wl[3], Wp4, 4, 9, 10, 12, 12);

    // dim-64 prop (h8 gathers)
    auto prop1 = [&](const half1* feat, const half1* sub, const half1* add,
                     half1* outh, float* outf, float scale, int bnrelu,
                     const float* g, const float* bb, const float* m, const float* v) {
        proph8_kernel<<<divup(NN * 8, 256), 256, 0, stream>>>(
            (const h8*)feat, (const h8*)sub, (const h8*)add,
            (h8*)outh, (f8*)outf, row_ptr, cw, NN, scale,
            sub != nullptr, bnrelu, g, bb, m, v);
    };
    // small-dim prop (half4 gathers)
    auto prop = [&](const half1* feat, const half1* sub, const half1* add,
                    half1* outh, float* outf, int dim4, float scale,
                    int bnrelu, int used, const float* g, const float* bb,
                    const float* m, const float* v) {
        proph_kernel<<<divup(NN * dim4, 256), 256, 0, stream>>>(
            (const half4*)feat, (const half4*)sub, (const half4*)add,
            (half4*)outh, (f4*)outf, row_ptr, cw, NN, dim4, scale,
            sub != nullptr, bnrelu, used, g, bb, m, v);
    };

    // ---- layer 1 (din=128, dout=64, K=8) -> H1f ----
    gemm_mfma_kernel<<<NB, 512, 0, stream>>>(Xh, Wt1, bl[0], CB1h, NN);
    {
        auto C = [&](int k) { return (const half1*)(CB1h + (size_t)k * NN * 64); };
        prop1(C(7), nullptr, C(6), S0, nullptr, 2.f, 0, 0, 0, 0, 0);
        prop1(S0, C(7), C(5), S1, nullptr, 2.f, 0, 0, 0, 0, 0);
        prop1(S1, S0, C(4), S2, nullptr, 2.f, 0, 0, 0, 0, 0);
        prop1(S2, S1, C(3), S0, nullptr, 2.f, 0, 0, 0, 0, 0);
        prop1(S0, S2, C(2), S1, nullptr, 2.f, 0, 0, 0, 0, 0);
        prop1(S1, S0, C(1), S2, nullptr, 2.f, 0, 0, 0, 0, 0);
        prop1(S2, S1, C(0), nullptr, H1f, 1.f, 1,
              bn[0][0], bn[0][1], bn[0][2], bn[0][3]);
    }

    // ---- layer 2 (din=64, dout=18 pad 20, K=6): X=H1f -> H2f ----
    gemm_smallw_kernel<6, 16, 5><<<NB, 384, 0, stream>>>(H1f, Wp2, bl[1], 18,
                                                         (half4*)CBsh, NN);
    {
        auto C = [&](int k) { return (const half1*)(CBsh + (size_t)k * NN * 20); };
        prop(C(5), nullptr, C(4), S0, nullptr, 5, 2.f, 0, 18, 0, 0, 0, 0);
        prop(S0, C(5), C(3), S1, nullptr, 5, 2.f, 0, 18, 0, 0, 0, 0);
        prop(S1, S0, C(2), S2, nullptr, 5, 2.f, 0, 18, 0, 0, 0, 0);
        prop(S2, S1, C(1), S0, nullptr, 5, 2.f, 0, 18, 0, 0, 0, 0);
        prop(S0, S2, C(0), nullptr, H2f, 5, 1.f, 1, 18,
             bn[1][0], bn[1][1], bn[1][2], bn[1][3]);
    }

    // ---- layer 3 (din=18 str20, dout=9 pad 12, K=4): X=H2f -> H3f ----
    gemm_smallw_kernel<4, 5, 3><<<NB, 256, 0, stream>>>(H2f, Wp3, bl[2], 9,
                                                        (half4*)CBsh, NN);
    {
        auto C = [&](int k) { return (const half1*)(CBsh + (size_t)k * NN * 12); };
        prop(C(3), nullptr, C(2), S0, nullptr, 3, 2.f, 0, 9, 0, 0, 0, 0);
        prop(S0, C(3), C(1), S1, nullptr, 3, 2.f, 0, 9, 0, 0, 0, 0);
        prop(S1, S0, C(0), nullptr, H3f, 3, 1.f, 1, 9,
             bn[2][0], bn[2][1], bn[2][2], bn[2][3]);
    }

    // ---- layer 4 (din=9 str12, dout=10 pad 12, K=4): X=H3f -> d_out ----
    gemm_smallw_kernel<4, 3, 3><<<NB, 256, 0, stream>>>(H3f, Wp4, bl[3], 10,
                                                        (half4*)CBsh, NN);
    {
        auto C = [&](int k) { return (const half1*)(CBsh + (size_t)k * NN * 12); };
        prop(C(3), nullptr, C(2), S0, nullptr, 3, 2.f, 0, 10, 0, 0, 0, 0);
        prop(S0, C(3), C(1), S1, nullptr, 3, 2.f, 0, 10, 0, 0, 0, 0);
        propl_kernel<<<divup(NN * 3, 256), 256, 0, stream>>>(
            (const half4*)S1, (const half4*)S0, (const half4*)CBsh,
            (float*)d_out, row_ptr, cw, NN);
    }
}